// Round 1
// baseline (1010.821 us; speedup 1.0000x reference)
//
#include <hip/hip_runtime.h>
#include <cstdint>
#include <cstddef>
#include <math.h>

// Problem constants (from setup_inputs): N=2, L=S=2048, Hd=512, H=8, E=64, TOPK=32
#define NH     8
#define EH     64
#define HD     512
#define NBATCH 2
#define LSEQ   2048
#define TK     32

// ws layout (f32): q[2][8][2048][64] | k[...] | v[...]  => 3 * 8 MiB = 24 MiB needed
// out layout (f32): V[2][2048][512] then A[2][8][2048][2048]

// ---------------------------------------------------------------------------
// Kernel 1: fused projections  out = X @ W^T + b, stored head-major
// out[((n*H+h)*L + s)*E + e],  o = h*64+e
// 64x64 output tile, K-chunks of 32 f32, XOR-swizzled LDS, float4 loads.
// Accumulation order: strictly ascending k (deterministic).
// ---------------------------------------------------------------------------
__global__ __launch_bounds__(256) void proj_kernel(
    const float* __restrict__ Xq, const float* __restrict__ Xk, const float* __restrict__ Xv,
    const float* __restrict__ Wq, const float* __restrict__ Bq,
    const float* __restrict__ Wk, const float* __restrict__ Bk,
    const float* __restrict__ Wv, const float* __restrict__ Bv,
    float* __restrict__ ws)
{
    const int z = blockIdx.z;
    const float* X = (z == 0) ? Xq : (z == 1) ? Xk : Xv;
    const float* W = (z == 0) ? Wq : (z == 1) ? Wk : Wv;
    const float* B = (z == 0) ? Bq : (z == 1) ? Bk : Bv;
    float* out = ws + (size_t)z * ((size_t)NBATCH * LSEQ * HD);

    __shared__ float4 Xs[64 * 8];   // 64 rows x 32 f32 (8 chunks), swizzled
    __shared__ float4 Ws[64 * 8];

    const int tid = threadIdx.x;
    const int tx = tid & 15, ty = tid >> 4;      // 16x16 thread grid, 4x4 micro-tile
    const int m0 = blockIdx.x * 64, n0 = blockIdx.y * 64;

    float acc[4][4];
    #pragma unroll
    for (int i = 0; i < 4; ++i)
        #pragma unroll
        for (int j = 0; j < 4; ++j) acc[i][j] = 0.f;

    for (int k0 = 0; k0 < HD; k0 += 32) {
        #pragma unroll
        for (int it = 0; it < 2; ++it) {
            int f = tid + it * 256;
            int row = f >> 3, c = f & 7;
            int cs = c ^ ((row >> 2) & 7);   // swizzle: spreads b-reads across bank groups
            Xs[row * 8 + cs] = *(const float4*)&X[(size_t)(m0 + row) * HD + k0 + c * 4];
            Ws[row * 8 + cs] = *(const float4*)&W[(size_t)(n0 + row) * HD + k0 + c * 4];
        }
        __syncthreads();
        #pragma unroll
        for (int c = 0; c < 8; ++c) {
            float4 av[4], bv4[4];
            #pragma unroll
            for (int i = 0; i < 4; ++i) { int r = ty * 4 + i; av[i]  = Xs[r * 8 + (c ^ ((r >> 2) & 7))]; }
            #pragma unroll
            for (int j = 0; j < 4; ++j) { int r = tx * 4 + j; bv4[j] = Ws[r * 8 + (c ^ ((r >> 2) & 7))]; }
            #pragma unroll
            for (int i = 0; i < 4; ++i)
                #pragma unroll
                for (int j = 0; j < 4; ++j) {
                    acc[i][j] = fmaf(av[i].x, bv4[j].x, acc[i][j]);
                    acc[i][j] = fmaf(av[i].y, bv4[j].y, acc[i][j]);
                    acc[i][j] = fmaf(av[i].z, bv4[j].z, acc[i][j]);
                    acc[i][j] = fmaf(av[i].w, bv4[j].w, acc[i][j]);
                }
        }
        __syncthreads();
    }

    #pragma unroll
    for (int j = 0; j < 4; ++j) {
        int o = n0 + tx * 4 + j;
        float bb = B[o];
        int h = o >> 6, e = o & 63;
        #pragma unroll
        for (int i = 0; i < 4; ++i) {
            int m = m0 + ty * 4 + i;
            int n = m >> 11, s = m & 2047;
            out[((size_t)((n * NH + h) * LSEQ + s)) * EH + e] = acc[i][j] + bb;
        }
    }
}

// ---------------------------------------------------------------------------
// Kernel 2: fused QK^T -> exact top-32 (radix select) -> softmax -> A, V
// One block (256 thr, 4 waves) per (n, h, 16 q-rows).
// LDS: scores[16][2048] f32 (128KiB) + k-tile (16KiB, swizzled) + q (4KiB).
// Phase B reuses kt4 as per-wave radix histograms and qs4 as top-32 lists.
// ---------------------------------------------------------------------------
__global__ __launch_bounds__(256) void attn_kernel(
    const float* __restrict__ ws, float* __restrict__ outV, float* __restrict__ outA)
{
    const float* qw = ws;
    const float* kw = ws + (size_t)NBATCH * LSEQ * HD;
    const float* vw = ws + (size_t)2 * NBATCH * LSEQ * HD;

    __shared__ float scores[16][LSEQ];   // 131072 B
    __shared__ float4 kt4[64 * 16];      // 16384 B (phase B: radix bins)
    __shared__ float4 qs4[16 * 16];      // 4096 B  (phase B: top lists)
    __shared__ unsigned cnts[4];

    const int tid  = threadIdx.x;
    const int lane = tid & 63;
    const int wv   = tid >> 6;
    const int l0   = blockIdx.x * 16;
    const int h    = blockIdx.y, n = blockIdx.z;
    const size_t headoff = (size_t)(n * NH + h) * LSEQ * EH;

    // load q tile: 16 rows x 16 float4-chunks (broadcast-read later, no swizzle needed)
    {
        int row = tid >> 4, c = tid & 15;
        qs4[row * 16 + c] = *(const float4*)&qw[headoff + (size_t)(l0 + row) * EH + c * 4];
    }

    // ---- Phase A: scores[r][s] = q_r . k_s  (exact f32, ascending-e order) ----
    for (int t = 0; t < 32; ++t) {
        #pragma unroll
        for (int it = 0; it < 4; ++it) {
            int f = tid + it * 256;
            int kr = f >> 4, c = f & 15;
            kt4[kr * 16 + (c ^ (kr & 7))] =
                *(const float4*)&kw[headoff + (size_t)(t * 64 + kr) * EH + c * 4];
        }
        __syncthreads();
        float a0 = 0.f, a1 = 0.f, a2 = 0.f, a3 = 0.f;
        #pragma unroll
        for (int c = 0; c < 16; ++c) {
            float4 kv = kt4[lane * 16 + (c ^ (lane & 7))];
            float4 q0 = qs4[(wv + 0)  * 16 + c];
            float4 q1 = qs4[(wv + 4)  * 16 + c];
            float4 q2 = qs4[(wv + 8)  * 16 + c];
            float4 q3 = qs4[(wv + 12) * 16 + c];
            a0 = fmaf(q0.x, kv.x, a0); a0 = fmaf(q0.y, kv.y, a0);
            a0 = fmaf(q0.z, kv.z, a0); a0 = fmaf(q0.w, kv.w, a0);
            a1 = fmaf(q1.x, kv.x, a1); a1 = fmaf(q1.y, kv.y, a1);
            a1 = fmaf(q1.z, kv.z, a1); a1 = fmaf(q1.w, kv.w, a1);
            a2 = fmaf(q2.x, kv.x, a2); a2 = fmaf(q2.y, kv.y, a2);
            a2 = fmaf(q2.z, kv.z, a2); a2 = fmaf(q2.w, kv.w, a2);
            a3 = fmaf(q3.x, kv.x, a3); a3 = fmaf(q3.y, kv.y, a3);
            a3 = fmaf(q3.z, kv.z, a3); a3 = fmaf(q3.w, kv.w, a3);
        }
        scores[wv + 0 ][t * 64 + lane] = a0;
        scores[wv + 4 ][t * 64 + lane] = a1;
        scores[wv + 8 ][t * 64 + lane] = a2;
        scores[wv + 12][t * 64 + lane] = a3;
        __syncthreads();
    }

    // ---- Phases B-E: per-wave rows 4*wv .. 4*wv+3, block-lockstep barriers ----
    unsigned* bins = (unsigned*)kt4 + wv * 256;  // 256 bins per wave
    unsigned* Lidx = (unsigned*)qs4 + wv * 64;   // 32 selected indices
    unsigned* Lval = Lidx + 32;                  // 32 keys -> later weights
    const float temp = 0.125f;                   // 1/sqrt(64)

    for (int rr = 0; rr < 4; ++rr) {
        const int r = wv * 4 + rr;
        const int l = l0 + r;

        // order-preserving u32 keys, lane owns s = {lane, lane+64, ...}
        unsigned key[32];
        #pragma unroll
        for (int t = 0; t < 32; ++t) {
            unsigned u = __float_as_uint(scores[r][t * 64 + lane]);
            key[t] = (u & 0x80000000u) ? ~u : (u | 0x80000000u);
        }

        // --- radix select: find threshold key T of the 32nd largest ---
        unsigned prefix = 0, prefmask = 0;
        int need = TK;
        #pragma unroll
        for (int pass = 0; pass < 4; ++pass) {
            const int shift = 24 - 8 * pass;
            #pragma unroll
            for (int i = 0; i < 4; ++i) bins[lane + 64 * i] = 0;
            __syncthreads();
            #pragma unroll
            for (int t = 0; t < 32; ++t) {
                if ((key[t] & prefmask) == prefix)
                    atomicAdd(&bins[(key[t] >> shift) & 255u], 1u);
            }
            __syncthreads();
            unsigned b0 = bins[lane * 4 + 0], b1 = bins[lane * 4 + 1],
                     b2 = bins[lane * 4 + 2], b3 = bins[lane * 4 + 3];
            unsigned tot  = b0 + b1 + b2 + b3;
            unsigned incl = tot;
            #pragma unroll
            for (int d = 1; d < 64; d <<= 1) {
                unsigned y = __shfl_down(incl, d);
                incl += (lane + d < 64) ? y : 0u;
            }
            unsigned tail = incl - tot;          // # keys in lanes > this lane
            unsigned S3 = tail, S2 = tail + b3, S1 = S2 + b2, S0 = S1 + b1;
            int dloc = -1; unsigned Sd = 0;
            if ((int)S3 < need && (int)(S3 + b3) >= need) { dloc = 3; Sd = S3; }
            if ((int)S2 < need && (int)(S2 + b2) >= need) { dloc = 2; Sd = S2; }
            if ((int)S1 < need && (int)(S1 + b1) >= need) { dloc = 1; Sd = S1; }
            if ((int)S0 < need && (int)(S0 + b0) >= need) { dloc = 0; Sd = S0; }
            unsigned long long bal = __ballot(dloc >= 0);
            int wl = __ffsll((unsigned long long)bal) - 1;
            unsigned pk = __shfl((dloc >= 0) ? (((unsigned)dloc << 16) | Sd) : 0u, wl);
            int dsel = 4 * wl + (int)(pk >> 16);
            prefix  |= ((unsigned)dsel) << shift;
            prefmask |= 0xFFu << shift;
            need    -= (int)(pk & 0xFFFFu);
            __syncthreads();
        }
        const unsigned T = prefix;   // exact key of the 32nd largest
        const int needEq = need;     // # to take among == T (>=1), by lowest index

        // --- collect: strict > T (unordered), == T by ascending index ---
        if (lane == 0) cnts[wv] = 0;
        __syncthreads();
        unsigned eqmask = 0u;
        #pragma unroll
        for (int t = 0; t < 32; ++t) {
            unsigned kt = key[t];
            if (kt > T) {
                unsigned p = atomicAdd(&cnts[wv], 1u);
                Lidx[p] = (unsigned)(t * 64 + lane);
                Lval[p] = kt;
            } else if (kt == T) {
                eqmask |= (1u << t);
            }
        }
        __syncthreads();
        const int base = TK - needEq;
        for (int e2 = 0; e2 < needEq; ++e2) {    // wave-local, no barriers inside
            unsigned mymin = 0xFFFFFFFFu;
            #pragma unroll
            for (int t = 0; t < 32; ++t)
                if ((eqmask >> t) & 1u) {
                    unsigned gi = (unsigned)(t * 64 + lane);
                    if (gi < mymin) mymin = gi;
                }
            unsigned mn = mymin;
            #pragma unroll
            for (int d = 1; d < 64; d <<= 1) {
                unsigned o2 = __shfl_xor(mn, d);
                mn = (o2 < mn) ? o2 : mn;
            }
            if (mymin == mn && mn != 0xFFFFFFFFu) {   // unique owner lane
                eqmask &= ~(1u << (mn >> 6));
                Lidx[base + e2] = mn;
                Lval[base + e2] = T;
            }
        }
        __syncthreads();

        // --- softmax over the 32 kept (lanes 0..31) ---
        float x = -INFINITY;
        unsigned gidx = 0u;
        if (lane < TK) {
            unsigned kk2 = Lval[lane];
            unsigned uu  = (kk2 & 0x80000000u) ? (kk2 ^ 0x80000000u) : ~kk2;
            x = temp * __uint_as_float(uu);
            gidx = Lidx[lane];
        }
        float mx = x;
        #pragma unroll
        for (int d = 1; d < 64; d <<= 1) mx = fmaxf(mx, __shfl_xor(mx, d));
        float ee = (lane < TK) ? expf(x - mx) : 0.f;
        float Z = ee;
        #pragma unroll
        for (int d = 1; d < 64; d <<= 1) Z += __shfl_xor(Z, d);
        float w = ee / Z;
        __syncthreads();
        if (lane < TK) Lval[lane] = __float_as_uint(w);  // stash weights
        __syncthreads();

        // --- A row: zeros + scatter in LDS, coalesced float4 store ---
        float4* srow = (float4*)&scores[r][0];
        const float4 z4 = make_float4(0.f, 0.f, 0.f, 0.f);
        #pragma unroll
        for (int u2 = 0; u2 < 8; ++u2) srow[lane + 64 * u2] = z4;
        __syncthreads();
        if (lane < TK) scores[r][gidx] = w;
        __syncthreads();
        float* Arow = outA + ((size_t)((n * NH + h) * LSEQ + l)) * LSEQ;
        #pragma unroll
        for (int u2 = 0; u2 < 8; ++u2)
            *(float4*)&Arow[(lane + 64 * u2) * 4] = srow[lane + 64 * u2];

        // --- V row: lanes <-> e, gather 32 weighted v rows ---
        float acc = 0.f;
        for (int i2 = 0; i2 < TK; ++i2) {
            unsigned gi = Lidx[i2];
            float wi = __uint_as_float(Lval[i2]);
            acc = fmaf(wi, vw[headoff + (size_t)gi * EH + lane], acc);
        }
        outV[((size_t)(n * LSEQ + l)) * HD + h * EH + lane] = acc;
        __syncthreads();
    }
}

// ---------------------------------------------------------------------------
extern "C" void kernel_launch(void* const* d_in, const int* in_sizes, int n_in,
                              void* d_out, int out_size, void* d_ws, size_t ws_size,
                              hipStream_t stream)
{
    (void)in_sizes; (void)n_in; (void)out_size; (void)ws_size;
    const float* q  = (const float*)d_in[0];
    const float* k  = (const float*)d_in[1];
    const float* v  = (const float*)d_in[2];
    const float* Wq = (const float*)d_in[3];
    const float* bq = (const float*)d_in[4];
    const float* Wk = (const float*)d_in[5];
    const float* bk = (const float*)d_in[6];
    const float* Wv = (const float*)d_in[7];
    const float* bv = (const float*)d_in[8];
    float* ws   = (float*)d_ws;  // needs 24 MiB
    float* outV = (float*)d_out;
    float* outA = outV + (size_t)NBATCH * LSEQ * HD;

    proj_kernel<<<dim3(64, 8, 3), 256, 0, stream>>>(q, k, v, Wq, bq, Wk, bk, Wv, bv, ws);
    attn_kernel<<<dim3(LSEQ / 16, NH, NBATCH), 256, 0, stream>>>(ws, outV, outA);
}

// Round 2
// 542.921 us; speedup vs baseline: 1.8618x; 1.8618x over previous
//
#include <hip/hip_runtime.h>
#include <cstdint>
#include <cstddef>
#include <math.h>

// Problem constants: N=2, L=S=2048, Hd=512, H=8, E=64, TOPK=32
#define NH     8
#define EH     64
#define HD     512
#define NBATCH 2
#define LSEQ   2048
#define TK     32

// ws layout (f32): q[2][8][2048][64] | k[...] | v[...]  => 24 MiB
// out layout (f32): V[2][2048][512] then A[2][8][2048][2048]

// ---------------------------------------------------------------------------
// Kernel 1: fused projections  out = X @ W^T + b, stored head-major (unchanged)
// ---------------------------------------------------------------------------
__global__ __launch_bounds__(256) void proj_kernel(
    const float* __restrict__ Xq, const float* __restrict__ Xk, const float* __restrict__ Xv,
    const float* __restrict__ Wq, const float* __restrict__ Bq,
    const float* __restrict__ Wk, const float* __restrict__ Bk,
    const float* __restrict__ Wv, const float* __restrict__ Bv,
    float* __restrict__ ws)
{
    const int z = blockIdx.z;
    const float* X = (z == 0) ? Xq : (z == 1) ? Xk : Xv;
    const float* W = (z == 0) ? Wq : (z == 1) ? Wk : Wv;
    const float* B = (z == 0) ? Bq : (z == 1) ? Bk : Bv;
    float* out = ws + (size_t)z * ((size_t)NBATCH * LSEQ * HD);

    __shared__ float4 Xs[64 * 8];
    __shared__ float4 Ws[64 * 8];

    const int tid = threadIdx.x;
    const int tx = tid & 15, ty = tid >> 4;
    const int m0 = blockIdx.x * 64, n0 = blockIdx.y * 64;

    float acc[4][4];
    #pragma unroll
    for (int i = 0; i < 4; ++i)
        #pragma unroll
        for (int j = 0; j < 4; ++j) acc[i][j] = 0.f;

    for (int k0 = 0; k0 < HD; k0 += 32) {
        #pragma unroll
        for (int it = 0; it < 2; ++it) {
            int f = tid + it * 256;
            int row = f >> 3, c = f & 7;
            int cs = c ^ ((row >> 2) & 7);
            Xs[row * 8 + cs] = *(const float4*)&X[(size_t)(m0 + row) * HD + k0 + c * 4];
            Ws[row * 8 + cs] = *(const float4*)&W[(size_t)(n0 + row) * HD + k0 + c * 4];
        }
        __syncthreads();
        #pragma unroll
        for (int c = 0; c < 8; ++c) {
            float4 av[4], bv4[4];
            #pragma unroll
            for (int i = 0; i < 4; ++i) { int r = ty * 4 + i; av[i]  = Xs[r * 8 + (c ^ ((r >> 2) & 7))]; }
            #pragma unroll
            for (int j = 0; j < 4; ++j) { int r = tx * 4 + j; bv4[j] = Ws[r * 8 + (c ^ ((r >> 2) & 7))]; }
            #pragma unroll
            for (int i = 0; i < 4; ++i)
                #pragma unroll
                for (int j = 0; j < 4; ++j) {
                    acc[i][j] = fmaf(av[i].x, bv4[j].x, acc[i][j]);
                    acc[i][j] = fmaf(av[i].y, bv4[j].y, acc[i][j]);
                    acc[i][j] = fmaf(av[i].z, bv4[j].z, acc[i][j]);
                    acc[i][j] = fmaf(av[i].w, bv4[j].w, acc[i][j]);
                }
        }
        __syncthreads();
    }

    #pragma unroll
    for (int j = 0; j < 4; ++j) {
        int o = n0 + tx * 4 + j;
        float bb = B[o];
        int h = o >> 6, e = o & 63;
        #pragma unroll
        for (int i = 0; i < 4; ++i) {
            int m = m0 + ty * 4 + i;
            int n = m >> 11, s = m & 2047;
            out[((size_t)((n * NH + h) * LSEQ + s)) * EH + e] = acc[i][j] + bb;
        }
    }
}

// ---------------------------------------------------------------------------
// Kernel 2: K-stationary fused QK^T -> exact top-32 -> softmax -> A, V
// Block = 512 thr (8 waves) per (n, h, 8 q-rows).
//   Phase A: wave wv owns k-tiles {4wv..4wv+3}; k rows in REGISTERS (lane=key,
//            64 VGPR), q streamed via wave-uniform scalar loads. Scores ->
//            LDS scores[8][2048] (64 KiB). One __syncthreads total.
//   Select:  wave wv owns row wv. Wave-private 256-bin radix (exact f32 keys),
//            tie-break lowest-index via ballot prefix ranks. No barriers.
// LDS = 64K scores + 8K bins = 72K -> 2 blocks/CU (16 waves, ~50% occupancy).
// ---------------------------------------------------------------------------
__device__ __forceinline__ unsigned f2key(float f) {
    unsigned u = __float_as_uint(f);
    return (u & 0x80000000u) ? ~u : (u | 0x80000000u);
}
__device__ __forceinline__ float key2f(unsigned k) {
    return __uint_as_float((k & 0x80000000u) ? (k ^ 0x80000000u) : ~k);
}

__global__ __launch_bounds__(512, 4) void attn_kernel(
    const float* __restrict__ ws, float* __restrict__ outV, float* __restrict__ outA)
{
    const float* qw = ws;
    const float* kw = ws + (size_t)NBATCH * LSEQ * HD;
    const float* vw = ws + (size_t)2 * NBATCH * LSEQ * HD;

    __shared__ float scores[8][LSEQ];        // 65536 B
    __shared__ unsigned binsArr[8 * 256];    // 8192 B (per-wave radix bins; reused as slots)

    const int tid  = threadIdx.x;
    const int lane = tid & 63;
    const int wv   = tid >> 6;

    // XCD-aware swizzle: 4096 blocks, 8 XCDs -> each XCD gets 512 consecutive
    // logical blocks = 2 full (n,h) heads -> k+v working set 2 MB fits L2.
    unsigned bid = blockIdx.x;
    unsigned id  = (bid & 7u) * 512u + (bid >> 3);
    const int n  = (int)(id >> 11);
    const int rem = (int)(id & 2047u);
    const int h  = rem >> 8;
    const int l0 = (rem & 255) * 8;
    const size_t headoff = (size_t)(n * NH + h) * LSEQ * EH;

    // ---- Phase A: wave wv computes k-tiles 4wv..4wv+3 for all 8 rows ----
    for (int tt = 0; tt < 4; ++tt) {
        const int t = wv * 4 + tt;
        // k row for this lane's key, in registers (L1 absorbs the stride-256 pattern)
        const float* kT = kw + headoff + (size_t)(t * 64 + lane) * EH;
        float4 kv[16];
        #pragma unroll
        for (int c = 0; c < 16; ++c) kv[c] = *(const float4*)&kT[c * 4];

        for (int row = 0; row < 8; ++row) {
            // wave-uniform address -> scalar loads (s_load), no LDS traffic
            const float* qB = qw + headoff + (size_t)(l0 + row) * EH;
            float acc = 0.f;
            #pragma unroll
            for (int c = 0; c < 16; ++c) {
                float4 kc = kv[c];
                acc = fmaf(qB[c * 4 + 0], kc.x, acc);
                acc = fmaf(qB[c * 4 + 1], kc.y, acc);
                acc = fmaf(qB[c * 4 + 2], kc.z, acc);
                acc = fmaf(qB[c * 4 + 3], kc.w, acc);
            }
            scores[row][t * 64 + lane] = acc;
        }
    }
    __syncthreads();   // the only block barrier

    // ---- Select phase: wave wv handles row wv; fully wave-local ----
    const int r = wv;
    const int l = l0 + r;
    const float temp = 0.125f;
    const unsigned long long lmlt = (1ull << lane) - 1ull;

    // sortable keys: lane owns s = lane + 64t
    unsigned key[32];
    #pragma unroll
    for (int t = 0; t < 32; ++t) key[t] = f2key(scores[r][t * 64 + lane]);

    unsigned* bins = binsArr + wv * 256;

    // radix select: exact key T of the 32nd largest (4 passes of 8 bits)
    unsigned prefix = 0, prefmask = 0;
    int need = TK;
    #pragma unroll
    for (int pass = 0; pass < 4; ++pass) {
        const int shift = 24 - 8 * pass;
        #pragma unroll
        for (int i = 0; i < 4; ++i) bins[lane + 64 * i] = 0;
        // (wave-private bins: compiler-inserted lgkmcnt orders write->atomic->read)
        #pragma unroll
        for (int t = 0; t < 32; ++t) {
            if ((key[t] & prefmask) == prefix)
                atomicAdd(&bins[(key[t] >> shift) & 255u], 1u);
        }
        unsigned b0 = bins[lane * 4 + 0], b1 = bins[lane * 4 + 1],
                 b2 = bins[lane * 4 + 2], b3 = bins[lane * 4 + 3];
        unsigned tot  = b0 + b1 + b2 + b3;
        unsigned incl = tot;
        #pragma unroll
        for (int d = 1; d < 64; d <<= 1) {
            unsigned y = __shfl_down(incl, d);
            incl += (lane + d < 64) ? y : 0u;
        }
        unsigned tail = incl - tot;              // keys with digit-owner lane > this lane
        unsigned S3 = tail, S2 = tail + b3, S1 = S2 + b2, S0 = S1 + b1;
        int dloc = -1; unsigned Sd = 0;
        if ((int)S3 < need && (int)(S3 + b3) >= need) { dloc = 3; Sd = S3; }
        if ((int)S2 < need && (int)(S2 + b2) >= need) { dloc = 2; Sd = S2; }
        if ((int)S1 < need && (int)(S1 + b1) >= need) { dloc = 1; Sd = S1; }
        if ((int)S0 < need && (int)(S0 + b0) >= need) { dloc = 0; Sd = S0; }
        unsigned long long bal = __ballot(dloc >= 0);
        int wl = __ffsll((unsigned long long)bal) - 1;
        unsigned pk = __shfl((dloc >= 0) ? (((unsigned)dloc << 16) | Sd) : 0u, wl);
        int dsel = 4 * wl + (int)(pk >> 16);
        prefix   |= ((unsigned)dsel) << shift;
        prefmask |= 0xFFu << shift;
        need     -= (int)(pk & 0xFFFFu);
    }
    const unsigned T = prefix;     // exact key of rank-32 element
    const int needEq = need;       // how many ==T to keep, lowest global index first

    // kept mask per lane (bit t), tie-break by ascending s = t*64+lane
    unsigned keptm = 0;
    {
        int cumeq = 0;
        #pragma unroll
        for (int t = 0; t < 32; ++t) {
            bool eq = (key[t] == T);
            unsigned long long b = __ballot(eq);
            int before = cumeq + __popcll(b & lmlt);
            if (key[t] > T || (eq && before < needEq)) keptm |= 1u << t;
            cumeq += __popcll(b);
        }
    }

    // global max (kept set contains it)
    unsigned mk = 0;
    #pragma unroll
    for (int t = 0; t < 32; ++t) mk = key[t] > mk ? key[t] : mk;
    #pragma unroll
    for (int d = 1; d < 64; d <<= 1) {
        unsigned o = __shfl_xor(mk, d);
        mk = o > mk ? o : mk;
    }
    const float M = key2f(mk);

    // Z = sum of exp over kept
    float Zp = 0.f;
    #pragma unroll
    for (int t = 0; t < 32; ++t)
        if ((keptm >> t) & 1u) Zp += expf(temp * (key2f(key[t]) - M));
    #pragma unroll
    for (int d = 1; d < 64; d <<= 1) Zp += __shfl_xor(Zp, d);
    const float invZ = 1.f / Zp;

    // A-row store (dense, includes the zeros) + slot list for V gather
    unsigned* slotS = bins;                 // reuse bins (radix done)
    float*    slotW = (float*)(bins + 32);
    float* Arow = outA + ((size_t)((n * NH + h) * LSEQ + l)) * LSEQ;
    {
        int cumk = 0;
        #pragma unroll
        for (int t = 0; t < 32; ++t) {
            bool kt = (keptm >> t) & 1u;
            float w = 0.f;
            if (kt) w = expf(temp * (key2f(key[t]) - M)) * invZ;
            Arow[t * 64 + lane] = w;
            unsigned long long b = __ballot(kt);
            if (kt) {
                int rank = cumk + __popcll(b & lmlt);
                slotS[rank] = (unsigned)(t * 64 + lane);
                slotW[rank] = w;
            }
            cumk += __popcll(b);
        }
    }

    // V row: gather 32 weighted v rows (slots broadcast from LDS, loads pipelined)
    float acc = 0.f;
    #pragma unroll
    for (int i = 0; i < TK; ++i) {
        unsigned s = slotS[i];
        float wgt  = slotW[i];
        acc = fmaf(wgt, vw[headoff + (size_t)s * EH + lane], acc);
    }
    outV[((size_t)(n * LSEQ + l)) * HD + h * EH + lane] = acc;
}

// ---------------------------------------------------------------------------
extern "C" void kernel_launch(void* const* d_in, const int* in_sizes, int n_in,
                              void* d_out, int out_size, void* d_ws, size_t ws_size,
                              hipStream_t stream)
{
    (void)in_sizes; (void)n_in; (void)out_size; (void)ws_size;
    const float* q  = (const float*)d_in[0];
    const float* k  = (const float*)d_in[1];
    const float* v  = (const float*)d_in[2];
    const float* Wq = (const float*)d_in[3];
    const float* bq = (const float*)d_in[4];
    const float* Wk = (const float*)d_in[5];
    const float* bk = (const float*)d_in[6];
    const float* Wv = (const float*)d_in[7];
    const float* bv = (const float*)d_in[8];
    float* ws   = (float*)d_ws;  // 24 MiB
    float* outV = (float*)d_out;
    float* outA = outV + (size_t)NBATCH * LSEQ * HD;

    proj_kernel<<<dim3(64, 8, 3), 256, 0, stream>>>(q, k, v, Wq, bq, Wk, bk, Wv, bv, ws);
    attn_kernel<<<dim3(4096, 1, 1), 512, 0, stream>>>(ws, outV, outA);
}

// Round 3
// 422.203 us; speedup vs baseline: 2.3942x; 1.2859x over previous
//
#include <hip/hip_runtime.h>
#include <cstdint>
#include <cstddef>
#include <math.h>

// Problem constants: N=2, L=S=2048, Hd=512, H=8, E=64, TOPK=32
#define NH     8
#define EH     64
#define HD     512
#define NBATCH 2
#define LSEQ   2048
#define TK     32

// ws layout (f32): q[2][8][2048][64] | kT[2][8][64][2048] | v[2][8][2048][64]
// out layout (f32): V[2][2048][512] then A[2][8][2048][2048]

// ---------------------------------------------------------------------------
// Kernel 1: fused projections  out = X @ W^T + b
//   z==0 (q), z==2 (v): head-major [n,h][s][e]
//   z==1 (k): TRANSPOSED  [n,h][e][s]  (for coalesced k-stationary QK)
// ---------------------------------------------------------------------------
__global__ __launch_bounds__(256) void proj_kernel(
    const float* __restrict__ Xq, const float* __restrict__ Xk, const float* __restrict__ Xv,
    const float* __restrict__ Wq, const float* __restrict__ Bq,
    const float* __restrict__ Wk, const float* __restrict__ Bk,
    const float* __restrict__ Wv, const float* __restrict__ Bv,
    float* __restrict__ ws)
{
    const int z = blockIdx.z;
    const float* X = (z == 0) ? Xq : (z == 1) ? Xk : Xv;
    const float* W = (z == 0) ? Wq : (z == 1) ? Wk : Wv;
    const float* B = (z == 0) ? Bq : (z == 1) ? Bk : Bv;
    float* out = ws + (size_t)z * ((size_t)NBATCH * LSEQ * HD);

    __shared__ float4 Xs[64 * 8];
    __shared__ float4 Ws[64 * 8];

    const int tid = threadIdx.x;
    const int tx = tid & 15, ty = tid >> 4;
    const int m0 = blockIdx.x * 64, n0 = blockIdx.y * 64;

    float acc[4][4];
    #pragma unroll
    for (int i = 0; i < 4; ++i)
        #pragma unroll
        for (int j = 0; j < 4; ++j) acc[i][j] = 0.f;

    for (int k0 = 0; k0 < HD; k0 += 32) {
        #pragma unroll
        for (int it = 0; it < 2; ++it) {
            int f = tid + it * 256;
            int row = f >> 3, c = f & 7;
            int cs = c ^ ((row >> 2) & 7);
            Xs[row * 8 + cs] = *(const float4*)&X[(size_t)(m0 + row) * HD + k0 + c * 4];
            Ws[row * 8 + cs] = *(const float4*)&W[(size_t)(n0 + row) * HD + k0 + c * 4];
        }
        __syncthreads();
        #pragma unroll
        for (int c = 0; c < 8; ++c) {
            float4 av[4], bv4[4];
            #pragma unroll
            for (int i = 0; i < 4; ++i) { int r = ty * 4 + i; av[i]  = Xs[r * 8 + (c ^ ((r >> 2) & 7))]; }
            #pragma unroll
            for (int j = 0; j < 4; ++j) { int r = tx * 4 + j; bv4[j] = Ws[r * 8 + (c ^ ((r >> 2) & 7))]; }
            #pragma unroll
            for (int i = 0; i < 4; ++i)
                #pragma unroll
                for (int j = 0; j < 4; ++j) {
                    acc[i][j] = fmaf(av[i].x, bv4[j].x, acc[i][j]);
                    acc[i][j] = fmaf(av[i].y, bv4[j].y, acc[i][j]);
                    acc[i][j] = fmaf(av[i].z, bv4[j].z, acc[i][j]);
                    acc[i][j] = fmaf(av[i].w, bv4[j].w, acc[i][j]);
                }
        }
        __syncthreads();
    }

    #pragma unroll
    for (int j = 0; j < 4; ++j) {
        int o = n0 + tx * 4 + j;
        float bb = B[o];
        int h = o >> 6, e = o & 63;
        #pragma unroll
        for (int i = 0; i < 4; ++i) {
            int m = m0 + ty * 4 + i;
            int n = m >> 11, s = m & 2047;
            float val = acc[i][j] + bb;
            if (z == 1)
                out[((size_t)((n * NH + h) * EH + e)) * LSEQ + s] = val;      // kT
            else
                out[((size_t)((n * NH + h) * LSEQ + s)) * EH + e] = val;
        }
    }
}

// ---------------------------------------------------------------------------
// Kernel 2: k-stationary QK^T (register acc, coalesced kT stream) ->
//           exact top-32 (wave-local radix) -> softmax -> A, V
// Block = 512 thr (8 waves), 8 q-rows. LDS 76KB -> 2 blocks/CU.
// Phase A: thread t owns keys 4t..4t+3; acc[8] float4 over e (static unroll).
// ---------------------------------------------------------------------------
__device__ __forceinline__ unsigned f2key(float f) {
    unsigned u = __float_as_uint(f);
    return (u & 0x80000000u) ? ~u : (u | 0x80000000u);
}
__device__ __forceinline__ float key2f(unsigned k) {
    return __uint_as_float((k & 0x80000000u) ? (k ^ 0x80000000u) : ~k);
}

__global__ __launch_bounds__(512, 4) void attn_kernel(
    const float* __restrict__ ws, float* __restrict__ outV, float* __restrict__ outA)
{
    const float* qw = ws;
    const float* kT = ws + (size_t)NBATCH * LSEQ * HD;   // [n,h][e][s]
    const float* vw = ws + (size_t)2 * NBATCH * LSEQ * HD;

    __shared__ float scores[8][LSEQ];        // 65536 B
    __shared__ float qs[EH * 8];             // [e][r], 2048 B
    __shared__ unsigned binsArr[8 * 256];    // 8192 B

    const int tid  = threadIdx.x;
    const int lane = tid & 63;
    const int wv   = tid >> 6;

    // XCD-aware swizzle: each XCD gets 512 consecutive logical blocks = 2 heads
    unsigned bid = blockIdx.x;
    unsigned id  = (bid & 7u) * 512u + (bid >> 3);
    const int n   = (int)(id >> 11);
    const int rem = (int)(id & 2047u);
    const int h   = rem >> 8;
    const int l0  = (rem & 255) * 8;
    const size_t headoff = (size_t)(n * NH + h) * LSEQ * EH;

    // stage q transposed into LDS: qs[e][r]
    {
        int r = tid >> 6, e = tid & 63;
        qs[e * 8 + r] = qw[headoff + (size_t)(l0 + r) * EH + e];
    }
    __syncthreads();

    // ---- Phase A: thread t computes scores[0..7][4t..4t+3] ----
    {
        const float* kp = kT + headoff + 4 * tid;
        float4 acc[8];
        #pragma unroll
        for (int r = 0; r < 8; ++r) acc[r] = make_float4(0.f, 0.f, 0.f, 0.f);

        #pragma unroll 8
        for (int e = 0; e < EH; ++e) {
            float4 kv = *(const float4*)(kp + (size_t)e * LSEQ);
            float4 qA = *(const float4*)&qs[e * 8 + 0];   // rows 0..3 (broadcast)
            float4 qB = *(const float4*)&qs[e * 8 + 4];   // rows 4..7
            acc[0].x = fmaf(qA.x, kv.x, acc[0].x); acc[0].y = fmaf(qA.x, kv.y, acc[0].y);
            acc[0].z = fmaf(qA.x, kv.z, acc[0].z); acc[0].w = fmaf(qA.x, kv.w, acc[0].w);
            acc[1].x = fmaf(qA.y, kv.x, acc[1].x); acc[1].y = fmaf(qA.y, kv.y, acc[1].y);
            acc[1].z = fmaf(qA.y, kv.z, acc[1].z); acc[1].w = fmaf(qA.y, kv.w, acc[1].w);
            acc[2].x = fmaf(qA.z, kv.x, acc[2].x); acc[2].y = fmaf(qA.z, kv.y, acc[2].y);
            acc[2].z = fmaf(qA.z, kv.z, acc[2].z); acc[2].w = fmaf(qA.z, kv.w, acc[2].w);
            acc[3].x = fmaf(qA.w, kv.x, acc[3].x); acc[3].y = fmaf(qA.w, kv.y, acc[3].y);
            acc[3].z = fmaf(qA.w, kv.z, acc[3].z); acc[3].w = fmaf(qA.w, kv.w, acc[3].w);
            acc[4].x = fmaf(qB.x, kv.x, acc[4].x); acc[4].y = fmaf(qB.x, kv.y, acc[4].y);
            acc[4].z = fmaf(qB.x, kv.z, acc[4].z); acc[4].w = fmaf(qB.x, kv.w, acc[4].w);
            acc[5].x = fmaf(qB.y, kv.x, acc[5].x); acc[5].y = fmaf(qB.y, kv.y, acc[5].y);
            acc[5].z = fmaf(qB.y, kv.z, acc[5].z); acc[5].w = fmaf(qB.y, kv.w, acc[5].w);
            acc[6].x = fmaf(qB.z, kv.x, acc[6].x); acc[6].y = fmaf(qB.z, kv.y, acc[6].y);
            acc[6].z = fmaf(qB.z, kv.z, acc[6].z); acc[6].w = fmaf(qB.z, kv.w, acc[6].w);
            acc[7].x = fmaf(qB.w, kv.x, acc[7].x); acc[7].y = fmaf(qB.w, kv.y, acc[7].y);
            acc[7].z = fmaf(qB.w, kv.z, acc[7].z); acc[7].w = fmaf(qB.w, kv.w, acc[7].w);
        }
        #pragma unroll
        for (int r = 0; r < 8; ++r)
            *(float4*)&scores[r][4 * tid] = acc[r];
    }
    __syncthreads();

    // ---- Select phase: wave wv handles row wv; fully wave-local ----
    const int r = wv;
    const int l = l0 + r;
    const float temp = 0.125f;
    const unsigned long long lmlt = (1ull << lane) - 1ull;

    unsigned key[32];
    #pragma unroll
    for (int t = 0; t < 32; ++t) key[t] = f2key(scores[r][t * 64 + lane]);

    unsigned* bins = binsArr + wv * 256;

    // radix select: exact key T of the 32nd largest (4 passes of 8 bits)
    unsigned prefix = 0, prefmask = 0;
    int need = TK;
    #pragma unroll
    for (int pass = 0; pass < 4; ++pass) {
        const int shift = 24 - 8 * pass;
        #pragma unroll
        for (int i = 0; i < 4; ++i) bins[lane + 64 * i] = 0;
        #pragma unroll
        for (int t = 0; t < 32; ++t) {
            if ((key[t] & prefmask) == prefix)
                atomicAdd(&bins[(key[t] >> shift) & 255u], 1u);
        }
        unsigned b0 = bins[lane * 4 + 0], b1 = bins[lane * 4 + 1],
                 b2 = bins[lane * 4 + 2], b3 = bins[lane * 4 + 3];
        unsigned tot  = b0 + b1 + b2 + b3;
        unsigned incl = tot;
        #pragma unroll
        for (int d = 1; d < 64; d <<= 1) {
            unsigned y = __shfl_down(incl, d);
            incl += (lane + d < 64) ? y : 0u;
        }
        unsigned tail = incl - tot;
        unsigned S3 = tail, S2 = tail + b3, S1 = S2 + b2, S0 = S1 + b1;
        int dloc = -1; unsigned Sd = 0;
        if ((int)S3 < need && (int)(S3 + b3) >= need) { dloc = 3; Sd = S3; }
        if ((int)S2 < need && (int)(S2 + b2) >= need) { dloc = 2; Sd = S2; }
        if ((int)S1 < need && (int)(S1 + b1) >= need) { dloc = 1; Sd = S1; }
        if ((int)S0 < need && (int)(S0 + b0) >= need) { dloc = 0; Sd = S0; }
        unsigned long long bal = __ballot(dloc >= 0);
        int wl = __ffsll((unsigned long long)bal) - 1;
        unsigned pk = __shfl((dloc >= 0) ? (((unsigned)dloc << 16) | Sd) : 0u, wl);
        int dsel = 4 * wl + (int)(pk >> 16);
        prefix   |= ((unsigned)dsel) << shift;
        prefmask |= 0xFFu << shift;
        need     -= (int)(pk & 0xFFFFu);
    }
    const unsigned T = prefix;
    const int needEq = need;

    // kept mask per lane (bit t), tie-break by ascending s = t*64+lane
    unsigned keptm = 0;
    {
        int cumeq = 0;
        #pragma unroll
        for (int t = 0; t < 32; ++t) {
            bool eq = (key[t] == T);
            unsigned long long b = __ballot(eq);
            int before = cumeq + __popcll(b & lmlt);
            if (key[t] > T || (eq && before < needEq)) keptm |= 1u << t;
            cumeq += __popcll(b);
        }
    }

    // global max
    unsigned mk = 0;
    #pragma unroll
    for (int t = 0; t < 32; ++t) mk = key[t] > mk ? key[t] : mk;
    #pragma unroll
    for (int d = 1; d < 64; d <<= 1) {
        unsigned o = __shfl_xor(mk, d);
        mk = o > mk ? o : mk;
    }
    const float M = key2f(mk);

    // Z = sum of exp over kept
    float Zp = 0.f;
    #pragma unroll
    for (int t = 0; t < 32; ++t)
        if ((keptm >> t) & 1u) Zp += __expf(temp * (key2f(key[t]) - M));
    #pragma unroll
    for (int d = 1; d < 64; d <<= 1) Zp += __shfl_xor(Zp, d);
    const float invZ = 1.f / Zp;

    // A-row store (dense zeros + weights) + slot list for V gather
    unsigned* slotS = bins;
    float*    slotW = (float*)(bins + 32);
    float* Arow = outA + ((size_t)((n * NH + h) * LSEQ + l)) * LSEQ;
    {
        int cumk = 0;
        #pragma unroll
        for (int t = 0; t < 32; ++t) {
            bool kt = (keptm >> t) & 1u;
            float w = 0.f;
            if (kt) w = __expf(temp * (key2f(key[t]) - M)) * invZ;
            Arow[t * 64 + lane] = w;
            unsigned long long b = __ballot(kt);
            if (kt) {
                int rank = cumk + __popcll(b & lmlt);
                slotS[rank] = (unsigned)(t * 64 + lane);
                slotW[rank] = w;
            }
            cumk += __popcll(b);
        }
    }

    // V row: gather 32 weighted v rows
    float acc = 0.f;
    #pragma unroll
    for (int i = 0; i < TK; ++i) {
        unsigned s = slotS[i];
        float wgt  = slotW[i];
        acc = fmaf(wgt, vw[headoff + (size_t)s * EH + lane], acc);
    }
    outV[((size_t)(n * LSEQ + l)) * HD + h * EH + lane] = acc;
}

// ---------------------------------------------------------------------------
extern "C" void kernel_launch(void* const* d_in, const int* in_sizes, int n_in,
                              void* d_out, int out_size, void* d_ws, size_t ws_size,
                              hipStream_t stream)
{
    (void)in_sizes; (void)n_in; (void)out_size; (void)ws_size;
    const float* q  = (const float*)d_in[0];
    const float* k  = (const float*)d_in[1];
    const float* v  = (const float*)d_in[2];
    const float* Wq = (const float*)d_in[3];
    const float* bq = (const float*)d_in[4];
    const float* Wk = (const float*)d_in[5];
    const float* bk = (const float*)d_in[6];
    const float* Wv = (const float*)d_in[7];
    const float* bv = (const float*)d_in[8];
    float* ws   = (float*)d_ws;  // 24 MiB
    float* outV = (float*)d_out;
    float* outA = outV + (size_t)NBATCH * LSEQ * HD;

    proj_kernel<<<dim3(64, 8, 3), 256, 0, stream>>>(q, k, v, Wq, bq, Wk, bk, Wv, bv, ws);
    attn_kernel<<<dim3(4096, 1, 1), 512, 0, stream>>>(ws, outV, outA);
}

// Round 4
// 297.863 us; speedup vs baseline: 3.3936x; 1.4174x over previous
//
#include <hip/hip_runtime.h>
#include <cstdint>
#include <cstddef>
#include <math.h>

// Problem constants: N=2, L=S=2048, Hd=512, H=8, E=64, TOPK=32
#define NH     8
#define EH     64
#define HD     512
#define NBATCH 2
#define LSEQ   2048
#define TK     32

// ws layout (f32): q[2][8][2048][64] | kT[2][8][64][2048] | v[2][8][2048][64]
// out layout (f32): V[2][2048][512] then A[2][8][2048][2048]

// ---------------------------------------------------------------------------
// Kernel 1: fused projections  out = X @ W^T + b   (unchanged from round 3)
//   z==0 (q), z==2 (v): head-major [n,h][s][e];  z==1 (k): transposed [n,h][e][s]
// ---------------------------------------------------------------------------
__global__ __launch_bounds__(256) void proj_kernel(
    const float* __restrict__ Xq, const float* __restrict__ Xk, const float* __restrict__ Xv,
    const float* __restrict__ Wq, const float* __restrict__ Bq,
    const float* __restrict__ Wk, const float* __restrict__ Bk,
    const float* __restrict__ Wv, const float* __restrict__ Bv,
    float* __restrict__ ws)
{
    const int z = blockIdx.z;
    const float* X = (z == 0) ? Xq : (z == 1) ? Xk : Xv;
    const float* W = (z == 0) ? Wq : (z == 1) ? Wk : Wv;
    const float* B = (z == 0) ? Bq : (z == 1) ? Bk : Bv;
    float* out = ws + (size_t)z * ((size_t)NBATCH * LSEQ * HD);

    __shared__ float4 Xs[64 * 8];
    __shared__ float4 Ws[64 * 8];

    const int tid = threadIdx.x;
    const int tx = tid & 15, ty = tid >> 4;
    const int m0 = blockIdx.x * 64, n0 = blockIdx.y * 64;

    float acc[4][4];
    #pragma unroll
    for (int i = 0; i < 4; ++i)
        #pragma unroll
        for (int j = 0; j < 4; ++j) acc[i][j] = 0.f;

    for (int k0 = 0; k0 < HD; k0 += 32) {
        #pragma unroll
        for (int it = 0; it < 2; ++it) {
            int f = tid + it * 256;
            int row = f >> 3, c = f & 7;
            int cs = c ^ ((row >> 2) & 7);
            Xs[row * 8 + cs] = *(const float4*)&X[(size_t)(m0 + row) * HD + k0 + c * 4];
            Ws[row * 8 + cs] = *(const float4*)&W[(size_t)(n0 + row) * HD + k0 + c * 4];
        }
        __syncthreads();
        #pragma unroll
        for (int c = 0; c < 8; ++c) {
            float4 av[4], bv4[4];
            #pragma unroll
            for (int i = 0; i < 4; ++i) { int r = ty * 4 + i; av[i]  = Xs[r * 8 + (c ^ ((r >> 2) & 7))]; }
            #pragma unroll
            for (int j = 0; j < 4; ++j) { int r = tx * 4 + j; bv4[j] = Ws[r * 8 + (c ^ ((r >> 2) & 7))]; }
            #pragma unroll
            for (int i = 0; i < 4; ++i)
                #pragma unroll
                for (int j = 0; j < 4; ++j) {
                    acc[i][j] = fmaf(av[i].x, bv4[j].x, acc[i][j]);
                    acc[i][j] = fmaf(av[i].y, bv4[j].y, acc[i][j]);
                    acc[i][j] = fmaf(av[i].z, bv4[j].z, acc[i][j]);
                    acc[i][j] = fmaf(av[i].w, bv4[j].w, acc[i][j]);
                }
        }
        __syncthreads();
    }

    #pragma unroll
    for (int j = 0; j < 4; ++j) {
        int o = n0 + tx * 4 + j;
        float bb = B[o];
        int h = o >> 6, e = o & 63;
        #pragma unroll
        for (int i = 0; i < 4; ++i) {
            int m = m0 + ty * 4 + i;
            int n = m >> 11, s = m & 2047;
            float val = acc[i][j] + bb;
            if (z == 1)
                out[((size_t)((n * NH + h) * EH + e)) * LSEQ + s] = val;      // kT
            else
                out[((size_t)((n * NH + h) * LSEQ + s)) * EH + e] = val;
        }
    }
}

// ---------------------------------------------------------------------------
// Kernel 2: k-stationary QK^T -> tau-prefiltered exact top-32 -> softmax -> A,V
// ---------------------------------------------------------------------------
__device__ __forceinline__ unsigned f2key(float f) {
    unsigned u = __float_as_uint(f);
    return (u & 0x80000000u) ? ~u : (u | 0x80000000u);
}
__device__ __forceinline__ float key2f(unsigned k) {
    return __uint_as_float((k & 0x80000000u) ? (k ^ 0x80000000u) : ~k);
}
__device__ __forceinline__ unsigned umax2(unsigned a, unsigned b) { return a > b ? a : b; }

__global__ __launch_bounds__(512, 4) void attn_kernel(
    const float* __restrict__ ws, float* __restrict__ outV, float* __restrict__ outA)
{
    const float* qw = ws;
    const float* kT = ws + (size_t)NBATCH * LSEQ * HD;   // [n,h][e][s]
    const float* vw = ws + (size_t)2 * NBATCH * LSEQ * HD;

    __shared__ float scores[8][LSEQ];              // 65536 B
    __shared__ float qs[EH * 8];                   // 2048 B
    __shared__ unsigned binsArr[8 * 256];          // 8192 B (radix bins / slot lists)
    __shared__ unsigned short candArr[8 * 256];    // 4096 B (candidate index lists)
    // total 79872 B -> 2 blocks/CU

    const int tid  = threadIdx.x;
    const int lane = tid & 63;
    const int wv   = tid >> 6;

    // XCD-aware swizzle: each XCD gets 512 consecutive logical blocks = 2 heads
    unsigned bid = blockIdx.x;
    unsigned id  = (bid & 7u) * 512u + (bid >> 3);
    const int n   = (int)(id >> 11);
    const int rem = (int)(id & 2047u);
    const int h   = rem >> 8;
    const int l0  = (rem & 255) * 8;
    const size_t headoff = (size_t)(n * NH + h) * LSEQ * EH;

    // stage q transposed into LDS: qs[e][r]
    {
        int r = tid >> 6, e = tid & 63;
        qs[e * 8 + r] = qw[headoff + (size_t)(l0 + r) * EH + e];
    }
    __syncthreads();

    // ---- Phase A: thread t computes scores[0..7][4t..4t+3] (exact f32) ----
    {
        const float* kp = kT + headoff + 4 * tid;
        float4 acc[8];
        #pragma unroll
        for (int r = 0; r < 8; ++r) acc[r] = make_float4(0.f, 0.f, 0.f, 0.f);

        #pragma unroll 8
        for (int e = 0; e < EH; ++e) {
            float4 kv = *(const float4*)(kp + (size_t)e * LSEQ);
            float4 qA = *(const float4*)&qs[e * 8 + 0];
            float4 qB = *(const float4*)&qs[e * 8 + 4];
            acc[0].x = fmaf(qA.x, kv.x, acc[0].x); acc[0].y = fmaf(qA.x, kv.y, acc[0].y);
            acc[0].z = fmaf(qA.x, kv.z, acc[0].z); acc[0].w = fmaf(qA.x, kv.w, acc[0].w);
            acc[1].x = fmaf(qA.y, kv.x, acc[1].x); acc[1].y = fmaf(qA.y, kv.y, acc[1].y);
            acc[1].z = fmaf(qA.y, kv.z, acc[1].z); acc[1].w = fmaf(qA.y, kv.w, acc[1].w);
            acc[2].x = fmaf(qA.z, kv.x, acc[2].x); acc[2].y = fmaf(qA.z, kv.y, acc[2].y);
            acc[2].z = fmaf(qA.z, kv.z, acc[2].z); acc[2].w = fmaf(qA.z, kv.w, acc[2].w);
            acc[3].x = fmaf(qA.w, kv.x, acc[3].x); acc[3].y = fmaf(qA.w, kv.y, acc[3].y);
            acc[3].z = fmaf(qA.w, kv.z, acc[3].z); acc[3].w = fmaf(qA.w, kv.w, acc[3].w);
            acc[4].x = fmaf(qB.x, kv.x, acc[4].x); acc[4].y = fmaf(qB.x, kv.y, acc[4].y);
            acc[4].z = fmaf(qB.x, kv.z, acc[4].z); acc[4].w = fmaf(qB.x, kv.w, acc[4].w);
            acc[5].x = fmaf(qB.y, kv.x, acc[5].x); acc[5].y = fmaf(qB.y, kv.y, acc[5].y);
            acc[5].z = fmaf(qB.y, kv.z, acc[5].z); acc[5].w = fmaf(qB.y, kv.w, acc[5].w);
            acc[6].x = fmaf(qB.z, kv.x, acc[6].x); acc[6].y = fmaf(qB.z, kv.y, acc[6].y);
            acc[6].z = fmaf(qB.z, kv.z, acc[6].z); acc[6].w = fmaf(qB.z, kv.w, acc[6].w);
            acc[7].x = fmaf(qB.w, kv.x, acc[7].x); acc[7].y = fmaf(qB.w, kv.y, acc[7].y);
            acc[7].z = fmaf(qB.w, kv.z, acc[7].z); acc[7].w = fmaf(qB.w, kv.w, acc[7].w);
        }
        #pragma unroll
        for (int r = 0; r < 8; ++r)
            *(float4*)&scores[r][4 * tid] = acc[r];
    }
    __syncthreads();

    // ---- Select: wave wv owns row wv; tau-prefilter + candidate radix ----
    const int r = wv;
    const int l = l0 + r;
    const float temp = 0.125f;
    const unsigned long long lmlt = (1ull << lane) - 1ull;

    unsigned key[32];
    #pragma unroll
    for (int t = 0; t < 32; ++t) key[t] = f2key(scores[r][t * 64 + lane]);

    unsigned* bins  = binsArr + wv * 256;
    unsigned short* cand = candArr + wv * 256;
    unsigned* slotS = bins;                 // 32 indices (after radix done)
    float*    slotW = (float*)(bins + 32);  // 32 weights

    // 1. per-lane max (tree; compiler can fuse to v_max3_u32)
    unsigned mx;
    {
        unsigned m0_ = umax2(key[0], key[1]);
        #pragma unroll
        for (int t = 2; t < 32; ++t) m0_ = umax2(m0_, key[t]);
        mx = m0_;
    }
    // 2. bitonic sort of the 64 lane-maxima (ascending); tau = 32nd largest
    {
        unsigned v = mx;
        #pragma unroll
        for (int k = 2; k <= 64; k <<= 1) {
            #pragma unroll
            for (int j = k >> 1; j >= 1; j >>= 1) {
                unsigned o = __shfl_xor(v, j);
                bool up = ((lane & k) == 0);
                bool keepmin = (((lane & j) == 0) == up);
                unsigned lo = v < o ? v : o, hi = v > o ? v : o;
                v = keepmin ? lo : hi;
            }
        }
        mx = __shfl(v, 32);   // tau: T >= tau, candidates = keys >= tau
    }
    const unsigned tau = mx;

    // 3. compact candidates (list ordered by ascending global index s)
    int Nc = 0;
    #pragma unroll
    for (int t = 0; t < 32; ++t) {
        bool c = key[t] >= tau;
        unsigned long long b = __ballot(c);
        if (c) {
            int rank = Nc + __popcll(b & lmlt);
            if (rank < 256) cand[rank] = (unsigned short)(t * 64 + lane);
        }
        Nc += __popcll(b);
    }

    unsigned T; int needEq;

    if (Nc <= 256) {
        // ---- fast path: radix select over <=256 candidates (<=4 per lane) ----
        unsigned ckey[4]; int cs[4]; bool cvd[4];
        #pragma unroll
        for (int j = 0; j < 4; ++j) {
            int p = lane + 64 * j;
            cvd[j]  = (p < Nc);
            cs[j]   = cvd[j] ? (int)cand[p] : 0;
            ckey[j] = cvd[j] ? f2key(scores[r][cs[j]]) : 0u;
        }

        unsigned prefix = 0, prefmask = 0;
        int need = TK;
        #pragma unroll
        for (int pass = 0; pass < 4; ++pass) {
            const int shift = 24 - 8 * pass;
            #pragma unroll
            for (int i = 0; i < 4; ++i) bins[lane + 64 * i] = 0;
            #pragma unroll
            for (int j = 0; j < 4; ++j) {
                if (cvd[j] && (ckey[j] & prefmask) == prefix)
                    atomicAdd(&bins[(ckey[j] >> shift) & 255u], 1u);
            }
            unsigned b0 = bins[lane * 4 + 0], b1 = bins[lane * 4 + 1],
                     b2 = bins[lane * 4 + 2], b3 = bins[lane * 4 + 3];
            unsigned tot  = b0 + b1 + b2 + b3;
            unsigned incl = tot;
            #pragma unroll
            for (int d = 1; d < 64; d <<= 1) {
                unsigned y = __shfl_down(incl, d);
                incl += (lane + d < 64) ? y : 0u;
            }
            unsigned tail = incl - tot;
            unsigned S3 = tail, S2 = tail + b3, S1 = S2 + b2, S0 = S1 + b1;
            int dloc = -1; unsigned Sd = 0;
            if ((int)S3 < need && (int)(S3 + b3) >= need) { dloc = 3; Sd = S3; }
            if ((int)S2 < need && (int)(S2 + b2) >= need) { dloc = 2; Sd = S2; }
            if ((int)S1 < need && (int)(S1 + b1) >= need) { dloc = 1; Sd = S1; }
            if ((int)S0 < need && (int)(S0 + b0) >= need) { dloc = 0; Sd = S0; }
            unsigned long long bal = __ballot(dloc >= 0);
            int wl = __ffsll((unsigned long long)bal) - 1;
            unsigned pk = __shfl((dloc >= 0) ? (((unsigned)dloc << 16) | Sd) : 0u, wl);
            int dsel = 4 * wl + (int)(pk >> 16);
            prefix   |= ((unsigned)dsel) << shift;
            prefmask |= 0xFFu << shift;
            need     -= (int)(pk & 0xFFFFu);
        }
        T = prefix; needEq = need;

        // kept flags over list positions (ascending index == ascending list pos)
        unsigned keptc = 0;
        {
            int cumeq = 0;
            #pragma unroll
            for (int j = 0; j < 4; ++j) {
                bool eq = cvd[j] && (ckey[j] == T);
                unsigned long long b = __ballot(eq);
                int before = cumeq + __popcll(b & lmlt);
                bool kt = (cvd[j] && ckey[j] > T) || (eq && before < needEq);
                if (kt) keptc |= 1u << j;
                cumeq += __popcll(b);
            }
        }

        // global max (always a candidate)
        unsigned mk = 0;
        #pragma unroll
        for (int j = 0; j < 4; ++j) if (cvd[j]) mk = umax2(mk, ckey[j]);
        #pragma unroll
        for (int d = 1; d < 64; d <<= 1) mk = umax2(mk, __shfl_xor(mk, d));
        const float M = key2f(mk);

        // exp + Z
        float wj[4]; float Zp = 0.f;
        #pragma unroll
        for (int j = 0; j < 4; ++j) {
            bool kt = (keptc >> j) & 1u;
            wj[j] = kt ? __expf(temp * (key2f(ckey[j]) - M)) : 0.f;
            Zp += wj[j];
        }
        #pragma unroll
        for (int d = 1; d < 64; d <<= 1) Zp += __shfl_xor(Zp, d);
        const float invZ = 1.f / Zp;

        // slot list (32 entries)
        {
            int cumk = 0;
            #pragma unroll
            for (int j = 0; j < 4; ++j) {
                bool kt = (keptc >> j) & 1u;
                unsigned long long b = __ballot(kt);
                if (kt) {
                    int rank = cumk + __popcll(b & lmlt);
                    slotS[rank] = (unsigned)cs[j];
                    slotW[rank] = wj[j] * invZ;
                }
                cumk += __popcll(b);
            }
        }
    } else {
        // ---- fallback: full radix over all 2048 keys (round-3 proven path) ----
        unsigned prefix = 0, prefmask = 0;
        int need = TK;
        #pragma unroll
        for (int pass = 0; pass < 4; ++pass) {
            const int shift = 24 - 8 * pass;
            #pragma unroll
            for (int i = 0; i < 4; ++i) bins[lane + 64 * i] = 0;
            #pragma unroll
            for (int t = 0; t < 32; ++t) {
                if ((key[t] & prefmask) == prefix)
                    atomicAdd(&bins[(key[t] >> shift) & 255u], 1u);
            }
            unsigned b0 = bins[lane * 4 + 0], b1 = bins[lane * 4 + 1],
                     b2 = bins[lane * 4 + 2], b3 = bins[lane * 4 + 3];
            unsigned tot  = b0 + b1 + b2 + b3;
            unsigned incl = tot;
            #pragma unroll
            for (int d = 1; d < 64; d <<= 1) {
                unsigned y = __shfl_down(incl, d);
                incl += (lane + d < 64) ? y : 0u;
            }
            unsigned tail = incl - tot;
            unsigned S3 = tail, S2 = tail + b3, S1 = S2 + b2, S0 = S1 + b1;
            int dloc = -1; unsigned Sd = 0;
            if ((int)S3 < need && (int)(S3 + b3) >= need) { dloc = 3; Sd = S3; }
            if ((int)S2 < need && (int)(S2 + b2) >= need) { dloc = 2; Sd = S2; }
            if ((int)S1 < need && (int)(S1 + b1) >= need) { dloc = 1; Sd = S1; }
            if ((int)S0 < need && (int)(S0 + b0) >= need) { dloc = 0; Sd = S0; }
            unsigned long long bal = __ballot(dloc >= 0);
            int wl = __ffsll((unsigned long long)bal) - 1;
            unsigned pk = __shfl((dloc >= 0) ? (((unsigned)dloc << 16) | Sd) : 0u, wl);
            int dsel = 4 * wl + (int)(pk >> 16);
            prefix   |= ((unsigned)dsel) << shift;
            prefmask |= 0xFFu << shift;
            need     -= (int)(pk & 0xFFFFu);
        }
        T = prefix; needEq = need;

        unsigned keptm = 0;
        {
            int cumeq = 0;
            #pragma unroll
            for (int t = 0; t < 32; ++t) {
                bool eq = (key[t] == T);
                unsigned long long b = __ballot(eq);
                int before = cumeq + __popcll(b & lmlt);
                if (key[t] > T || (eq && before < needEq)) keptm |= 1u << t;
                cumeq += __popcll(b);
            }
        }
        unsigned mk = 0;
        #pragma unroll
        for (int t = 0; t < 32; ++t) mk = umax2(mk, key[t]);
        #pragma unroll
        for (int d = 1; d < 64; d <<= 1) mk = umax2(mk, __shfl_xor(mk, d));
        const float M = key2f(mk);

        float Zp = 0.f;
        #pragma unroll
        for (int t = 0; t < 32; ++t)
            if ((keptm >> t) & 1u) Zp += __expf(temp * (key2f(key[t]) - M));
        #pragma unroll
        for (int d = 1; d < 64; d <<= 1) Zp += __shfl_xor(Zp, d);
        const float invZ = 1.f / Zp;

        int cumk = 0;
        #pragma unroll
        for (int t = 0; t < 32; ++t) {
            bool kt = (keptm >> t) & 1u;
            unsigned long long b = __ballot(kt);
            if (kt) {
                int rank = cumk + __popcll(b & lmlt);
                slotS[rank] = (unsigned)(t * 64 + lane);
                slotW[rank] = __expf(temp * (key2f(key[t]) - M)) * invZ;
            }
            cumk += __popcll(b);
        }
    }

    // ---- common epilogue: A-row (LDS-staged) + V gather ----
    float4* srow = (float4*)&scores[r][0];
    const float4 z4 = make_float4(0.f, 0.f, 0.f, 0.f);
    #pragma unroll
    for (int u = 0; u < 8; ++u) srow[lane + 64 * u] = z4;
    if (lane < TK) scores[r][slotS[lane]] = slotW[lane];   // wave-local scatter
    float* Arow = outA + ((size_t)((n * NH + h) * LSEQ + l)) * LSEQ;
    #pragma unroll
    for (int u = 0; u < 8; ++u)
        *(float4*)&Arow[(lane + 64 * u) * 4] = srow[lane + 64 * u];

    float acc = 0.f;
    #pragma unroll
    for (int i = 0; i < TK; ++i) {
        unsigned s = slotS[i];
        float wgt  = slotW[i];
        acc = fmaf(wgt, vw[headoff + (size_t)s * EH + lane], acc);
    }
    outV[((size_t)(n * LSEQ + l)) * HD + h * EH + lane] = acc;
}

// ---------------------------------------------------------------------------
extern "C" void kernel_launch(void* const* d_in, const int* in_sizes, int n_in,
                              void* d_out, int out_size, void* d_ws, size_t ws_size,
                              hipStream_t stream)
{
    (void)in_sizes; (void)n_in; (void)out_size; (void)ws_size;
    const float* q  = (const float*)d_in[0];
    const float* k  = (const float*)d_in[1];
    const float* v  = (const float*)d_in[2];
    const float* Wq = (const float*)d_in[3];
    const float* bq = (const float*)d_in[4];
    const float* Wk = (const float*)d_in[5];
    const float* bk = (const float*)d_in[6];
    const float* Wv = (const float*)d_in[7];
    const float* bv = (const float*)d_in[8];
    float* ws   = (float*)d_ws;  // 24 MiB
    float* outV = (float*)d_out;
    float* outA = outV + (size_t)NBATCH * LSEQ * HD;

    proj_kernel<<<dim3(64, 8, 3), 256, 0, stream>>>(q, k, v, Wq, bq, Wk, bk, Wv, bv, ws);
    attn_kernel<<<dim3(4096, 1, 1), 512, 0, stream>>>(ws, outV, outA);
}

// Round 5
// 246.215 us; speedup vs baseline: 4.1054x; 1.2098x over previous
//
#include <hip/hip_runtime.h>
#include <cstdint>
#include <cstddef>
#include <math.h>

// Problem constants: N=2, L=S=2048, Hd=512, H=8, E=64, TOPK=32
#define NH     8
#define EH     64
#define HD     512
#define NBATCH 2
#define LSEQ   2048
#define TK     32

// ws layout: q f32 [0, 2097152) | k f32 row-major [2097152, 4194304) |
//            v f32 [4194304, 6291456) | khi bf16-frag u16 [6291456 f32 .. +4MB)
// => 28 MiB total.  khi frag: per head 128 key-tiles x 2 ksteps x 64 lanes x 8 u16.
// out layout (f32): V[2][2048][512] then A[2][8][2048][2048]

using f32x4  = __attribute__((ext_vector_type(4))) float;
using bf16x8 = __attribute__((ext_vector_type(8))) short;

__device__ __forceinline__ unsigned short f2b(float f) {   // f32 -> bf16 RNE bits
    unsigned u = __float_as_uint(f);
    return (unsigned short)((u + 0x7FFFu + ((u >> 16) & 1u)) >> 16);
}
__device__ __forceinline__ unsigned f2key(float f) {       // order-preserving u32
    unsigned u = __float_as_uint(f);
    return (u & 0x80000000u) ? ~u : (u | 0x80000000u);
}
__device__ __forceinline__ float key2f(unsigned k) {
    return __uint_as_float((k & 0x80000000u) ? (k ^ 0x80000000u) : ~k);
}

// ---------------------------------------------------------------------------
// Kernel 1: fused projections out = X @ W^T + b, row-major head-major for all;
// z==1 additionally emits khi (bf16) in MFMA B-fragment order.
// ---------------------------------------------------------------------------
__global__ __launch_bounds__(256) void proj_kernel(
    const float* __restrict__ Xq, const float* __restrict__ Xk, const float* __restrict__ Xv,
    const float* __restrict__ Wq, const float* __restrict__ Bq,
    const float* __restrict__ Wk, const float* __restrict__ Bk,
    const float* __restrict__ Wv, const float* __restrict__ Bv,
    float* __restrict__ ws)
{
    const int z = blockIdx.z;
    const float* X = (z == 0) ? Xq : (z == 1) ? Xk : Xv;
    const float* W = (z == 0) ? Wq : (z == 1) ? Wk : Wv;
    const float* B = (z == 0) ? Bq : (z == 1) ? Bk : Bv;
    float* out = ws + (size_t)z * 2097152;
    unsigned short* khi = (unsigned short*)(ws + 6291456);

    __shared__ float4 Xs[64 * 8];
    __shared__ float4 Ws[64 * 8];

    const int tid = threadIdx.x;
    const int tx = tid & 15, ty = tid >> 4;
    const int m0 = blockIdx.x * 64, n0 = blockIdx.y * 64;

    float acc[4][4];
    #pragma unroll
    for (int i = 0; i < 4; ++i)
        #pragma unroll
        for (int j = 0; j < 4; ++j) acc[i][j] = 0.f;

    for (int k0 = 0; k0 < HD; k0 += 32) {
        #pragma unroll
        for (int it = 0; it < 2; ++it) {
            int f = tid + it * 256;
            int row = f >> 3, c = f & 7;
            int cs = c ^ ((row >> 2) & 7);
            Xs[row * 8 + cs] = *(const float4*)&X[(size_t)(m0 + row) * HD + k0 + c * 4];
            Ws[row * 8 + cs] = *(const float4*)&W[(size_t)(n0 + row) * HD + k0 + c * 4];
        }
        __syncthreads();
        #pragma unroll
        for (int c = 0; c < 8; ++c) {
            float4 av[4], bv4[4];
            #pragma unroll
            for (int i = 0; i < 4; ++i) { int r = ty * 4 + i; av[i]  = Xs[r * 8 + (c ^ ((r >> 2) & 7))]; }
            #pragma unroll
            for (int j = 0; j < 4; ++j) { int r = tx * 4 + j; bv4[j] = Ws[r * 8 + (c ^ ((r >> 2) & 7))]; }
            #pragma unroll
            for (int i = 0; i < 4; ++i)
                #pragma unroll
                for (int j = 0; j < 4; ++j) {
                    acc[i][j] = fmaf(av[i].x, bv4[j].x, acc[i][j]);
                    acc[i][j] = fmaf(av[i].y, bv4[j].y, acc[i][j]);
                    acc[i][j] = fmaf(av[i].z, bv4[j].z, acc[i][j]);
                    acc[i][j] = fmaf(av[i].w, bv4[j].w, acc[i][j]);
                }
        }
        __syncthreads();
    }

    #pragma unroll
    for (int j = 0; j < 4; ++j) {
        int o = n0 + tx * 4 + j;
        float bb = B[o];
        int h = o >> 6, e = o & 63;
        #pragma unroll
        for (int i = 0; i < 4; ++i) {
            int m = m0 + ty * 4 + i;
            int n = m >> 11, s = m & 2047;
            float val = acc[i][j] + bb;
            int head = n * NH + h;
            out[(size_t)head * 131072 + (size_t)s * EH + e] = val;
            if (z == 1) {
                // MFMA B-frag: col=s&15, k-dim e: lane=((e&31)>>3)*16+(s&15), j=e&7
                int kt = s >> 4, ks = e >> 5;
                int lane = (((e & 31) >> 3) << 4) | (s & 15);
                size_t idx = ((((size_t)head * 128 + kt) * 2 + ks) * 64 + lane) * 8 + (e & 7);
                khi[idx] = f2b(val);
            }
        }
    }
}

// ---------------------------------------------------------------------------
// Kernel 2: MFMA bf16 approx QK^T -> tau-margin candidates -> exact f32
// rescore -> exact top-32 (u64 bitonic, tie=lowest idx) -> softmax -> A, V.
// Block = 512 thr (8 waves), 16 q-rows, 2048 blocks. LDS 72KB -> 2 blocks/CU.
// ---------------------------------------------------------------------------
__device__ __forceinline__ unsigned long long sort64_desc(unsigned long long v, int lane) {
    #pragma unroll
    for (int k = 2; k <= 64; k <<= 1)
        #pragma unroll
        for (int j = k >> 1; j >= 1; j >>= 1) {
            unsigned long long o = __shfl_xor(v, j, 64);
            bool up = ((lane & k) != 0);                 // flipped -> descending
            bool keepmin = (((lane & j) == 0) == up);
            unsigned long long lo = v < o ? v : o;
            unsigned long long hi = v > o ? v : o;
            v = keepmin ? lo : hi;
        }
    return v;
}
__device__ __forceinline__ unsigned long long merge_top64(unsigned long long a, unsigned long long b, int lane) {
    // a, b descending-sorted; returns top-64 of union, descending
    unsigned long long br = __shfl(b, 63 - lane, 64);
    unsigned long long m = a > br ? a : br;
    #pragma unroll
    for (int j = 32; j >= 1; j >>= 1) {
        unsigned long long o = __shfl_xor(m, j, 64);
        bool keepmax = ((lane & j) == 0);
        unsigned long long mx = m > o ? m : o;
        unsigned long long mn = m < o ? m : o;
        m = keepmax ? mx : mn;
    }
    return m;
}

__global__ __launch_bounds__(512, 4) void attn_kernel(
    const float* __restrict__ ws, float* __restrict__ outV, float* __restrict__ outA)
{
    const float* qw = ws;
    const float* kw = ws + 2097152;
    const float* vw = ws + 4194304;
    const unsigned short* khi = (const unsigned short*)(ws + 6291456);

    __shared__ unsigned short scores16[16 * 2048];   // 65536 B (u16 sortable keys)
    __shared__ float qs[EH * 16];                    // 4096 B, [e][row]
    __shared__ unsigned short candArr[8 * 256];      // 4096 B
    __shared__ unsigned cnts[8];

    const int tid  = threadIdx.x;
    const int lane = tid & 63;
    const int wv   = tid >> 6;

    // XCD swizzle: 2048 blocks, 256/XCD = 2 heads per XCD (k+v+q+khi ~3.5MB in L2)
    unsigned bid = blockIdx.x;
    unsigned id  = (bid & 7u) * 256u + (bid >> 3);
    const int head = (int)(id >> 7);           // n*8+h
    const int l0   = (int)(id & 127u) * 16;
    const size_t headoff = (size_t)head * 131072;

    // stage q: qs[e][row], rows l0..l0+15
    #pragma unroll
    for (int it = 0; it < 2; ++it) {
        int i = tid + it * 512;
        int row = i & 15, e = i >> 4;
        qs[i] = qw[headoff + (size_t)(l0 + row) * EH + e];
    }
    __syncthreads();

    // ---- Phase A: MFMA approx scores -> u16 keys in LDS ----
    {
        bf16x8 afrag[2];
        #pragma unroll
        for (int ks = 0; ks < 2; ++ks)
            #pragma unroll
            for (int j = 0; j < 8; ++j) {
                int e = ks * 32 + ((lane >> 4) << 3) + j;
                afrag[ks][j] = (short)f2b(qs[e * 16 + (lane & 15)]);
            }

        f32x4 acc[16];
        #pragma unroll
        for (int kt = 0; kt < 16; ++kt) acc[kt] = (f32x4)(0.f);

        const unsigned short* kb = khi + headoff * 2;  // head*262144 u16? NO:
        // khi per head = 131072 u16; headoff (=head*131072) counts f32 of q —
        // reuse numeric: head*131072 u16 is exactly the khi head stride.
        #pragma unroll
        for (int kt = 0; kt < 16; ++kt) {
            int ktg = wv * 16 + kt;
            #pragma unroll
            for (int ks = 0; ks < 2; ++ks) {
                bf16x8 b = *(const bf16x8*)(khi + (size_t)head * 131072 +
                              ((((size_t)ktg * 2 + ks) * 64 + lane) << 3));
                acc[kt] = __builtin_amdgcn_mfma_f32_16x16x32_bf16(afrag[ks], b, acc[kt], 0, 0, 0);
            }
        }
        (void)kb;
        #pragma unroll
        for (int kt = 0; kt < 16; ++kt) {
            int key = wv * 256 + kt * 16 + (lane & 15);
            #pragma unroll
            for (int reg = 0; reg < 4; ++reg) {
                int rr = ((lane >> 4) << 2) + reg;     // C: col=lane&15, row=(lane>>4)*4+reg
                scores16[rr * 2048 + key] = (unsigned short)(f2key(acc[kt][reg]) >> 16);
            }
        }
    }
    __syncthreads();

    // ---- Select: wave wv owns rows 2wv, 2wv+1; fully wave-local ----
    unsigned short* cand = candArr + wv * 256;
    int   rowS[2][1]; float rowW[2][1];  // per-lane slot (lanes 0..31 hold top-32)
    int selS[2]; float selW[2];

    #pragma unroll
    for (int rr2 = 0; rr2 < 2; ++rr2) {
        const int r = 2 * wv + rr2;
        const unsigned* srow32 = (const unsigned*)(scores16 + r * 2048);

        // 1. per-lane max over packed u16 pairs
        unsigned mx = 0;
        #pragma unroll
        for (int t = 0; t < 16; ++t) {
            unsigned vv = srow32[t * 64 + lane];
            unsigned a = vv & 0xFFFFu, b = vv >> 16;
            unsigned ab = a > b ? a : b;
            mx = mx > ab ? mx : ab;
        }
        // 2. bitonic ascending sort of lane maxima (round-4 proven); tau=rank-32
        {
            unsigned v = mx;
            #pragma unroll
            for (int k = 2; k <= 64; k <<= 1)
                #pragma unroll
                for (int j = k >> 1; j >= 1; j >>= 1) {
                    unsigned o = __shfl_xor(v, j);
                    bool up = ((lane & k) == 0);
                    bool keepmin = (((lane & j) == 0) == up);
                    unsigned lo = v < o ? v : o, hi = v > o ? v : o;
                    v = keepmin ? lo : hi;
                }
            mx = __shfl(v, 32);
        }
        const unsigned tau16 = mx;
        // 3. margin threshold in u16-key space (covers bf16 + trunc error)
        const float tauf = key2f(tau16 << 16);
        const unsigned thr16 = f2key(tauf - 0.35f) >> 16;

        // 4. collect candidates (unordered; sort fixes order later)
        if (lane == 0) cnts[wv] = 0;
        #pragma unroll
        for (int t = 0; t < 16; ++t) {
            unsigned vv = srow32[t * 64 + lane];
            unsigned i0 = (unsigned)((t * 64 + lane) * 2);
            if ((vv & 0xFFFFu) >= thr16) {
                unsigned p = atomicAdd(&cnts[wv], 1u);
                if (p < 256) cand[p] = (unsigned short)i0;
            }
            if ((vv >> 16) >= thr16) {
                unsigned p = atomicAdd(&cnts[wv], 1u);
                if (p < 256) cand[p] = (unsigned short)(i0 + 1);
            }
        }
        int Nc = (int)cnts[wv];          // DS pipe is in-order within a wave
        if (Nc > 256) Nc = 256;
        const int nch = (Nc + 63) >> 6;

        // 5. exact rescore + exact top-32 via u64 bitonic (desc), chunk-merged
        unsigned long long best = 0ull;
        for (int c = 0; c < nch; ++c) {
            int p = c * 64 + lane;
            bool valid = p < Nc;
            int si = valid ? (int)cand[p] : 0;
            float sc = 0.f;
            if (valid) {
                const float* krow = kw + headoff + (size_t)si * EH;
                #pragma unroll
                for (int c4 = 0; c4 < 16; ++c4) {      // ascending e: bit-identical
                    float4 kv = *(const float4*)&krow[c4 * 4];
                    sc = fmaf(qs[(c4 * 4 + 0) * 16 + r], kv.x, sc);
                    sc = fmaf(qs[(c4 * 4 + 1) * 16 + r], kv.y, sc);
                    sc = fmaf(qs[(c4 * 4 + 2) * 16 + r], kv.z, sc);
                    sc = fmaf(qs[(c4 * 4 + 3) * 16 + r], kv.w, sc);
                }
            }
            unsigned long long comp = valid
                ? ((((unsigned long long)f2key(sc)) << 32) | (unsigned)(~si))
                : 0ull;
            comp = sort64_desc(comp, lane);
            best = (c == 0) ? comp : merge_top64(best, comp, lane);
        }

        // 6. softmax over lanes 0..31 (rank order; lane0 = max)
        unsigned key32 = (unsigned)(best >> 32);
        int si = (int)(~((unsigned)best)) & 2047;
        float sc = key2f(key32);
        float M = __shfl(sc, 0);
        float ee = (lane < TK) ? __expf(0.125f * (sc - M)) : 0.f;
        float Z = ee;
        #pragma unroll
        for (int d = 1; d < 64; d <<= 1) Z += __shfl_xor(Z, d);
        selS[rr2] = si;
        selW[rr2] = ee / Z;
    }
    rowS[0][0] = selS[0]; rowW[0][0] = selW[0];
    rowS[1][0] = selS[1]; rowW[1][0] = selW[1];

    // ---- Epilogue: A rows (stage in own 8KB scores region) + V rows ----
    float* abuf = (float*)((char*)scores16 + wv * 8192);   // 2048 f32, wave-private
    const int n = head >> 3, h = head & 7;
    #pragma unroll
    for (int rr2 = 0; rr2 < 2; ++rr2) {
        const int lrow = l0 + 2 * wv + rr2;
        float4* ab4 = (float4*)abuf;
        const float4 z4 = make_float4(0.f, 0.f, 0.f, 0.f);
        #pragma unroll
        for (int u = 0; u < 8; ++u) ab4[u * 64 + lane] = z4;
        if (lane < TK) abuf[rowS[rr2][0]] = rowW[rr2][0];
        float* Arow = outA + ((size_t)head * 2048 + lrow) * 2048;
        #pragma unroll
        for (int u = 0; u < 8; ++u)
            *(float4*)&Arow[(u * 64 + lane) * 4] = ab4[u * 64 + lane];

        float acc = 0.f;
        #pragma unroll
        for (int i = 0; i < TK; ++i) {
            int s_i   = __shfl(rowS[rr2][0], i);
            float w_i = __shfl(rowW[rr2][0], i);
            acc = fmaf(w_i, vw[headoff + (size_t)s_i * EH + lane], acc);
        }
        outV[((size_t)(n * 2048 + lrow)) * 512 + h * 64 + lane] = acc;
    }
}

// ---------------------------------------------------------------------------
extern "C" void kernel_launch(void* const* d_in, const int* in_sizes, int n_in,
                              void* d_out, int out_size, void* d_ws, size_t ws_size,
                              hipStream_t stream)
{
    (void)in_sizes; (void)n_in; (void)out_size; (void)ws_size;
    const float* q  = (const float*)d_in[0];
    const float* k  = (const float*)d_in[1];
    const float* v  = (const float*)d_in[2];
    const float* Wq = (const float*)d_in[3];
    const float* bq = (const float*)d_in[4];
    const float* Wk = (const float*)d_in[5];
    const float* bk = (const float*)d_in[6];
    const float* Wv = (const float*)d_in[7];
    const float* bv = (const float*)d_in[8];
    float* ws   = (float*)d_ws;  // 28 MiB
    float* outV = (float*)d_out;
    float* outA = outV + (size_t)NBATCH * LSEQ * HD;

    proj_kernel<<<dim3(64, 8, 3), 256, 0, stream>>>(q, k, v, Wq, bq, Wk, bk, Wv, bv, ws);
    attn_kernel<<<dim3(2048, 1, 1), 512, 0, stream>>>(ws, outV, outA);
}

// Round 6
// 221.642 us; speedup vs baseline: 4.5606x; 1.1109x over previous
//
#include <hip/hip_runtime.h>
#include <cstdint>
#include <cstddef>
#include <math.h>

// Problem constants: N=2, L=S=2048, Hd=512, H=8, E=64, TOPK=32
#define NH     8
#define EH     64
#define HD     512
#define NBATCH 2
#define LSEQ   2048
#define TK     32

// ws layout: q f32 [0, 2097152) | k f32 row-major [2097152, 4194304) |
//            v f32 [4194304, 6291456) | khi bf16-frag u16 at ws+6291456 (4 MiB)
// khi: per head 128 key-tiles x 2 ksteps x 64 lanes x 8 u16 (= 131072 u16/head).
// out layout (f32): V[2][2048][512] then A[2][8][2048][2048]

using f32x4  = __attribute__((ext_vector_type(4))) float;
using bf16x8 = __attribute__((ext_vector_type(8))) short;
using u16x8  = __attribute__((ext_vector_type(8))) unsigned short;

__device__ __forceinline__ unsigned short f2b(float f) {   // f32 -> bf16 RNE bits
    unsigned u = __float_as_uint(f);
    return (unsigned short)((u + 0x7FFFu + ((u >> 16) & 1u)) >> 16);
}
__device__ __forceinline__ unsigned f2key(float f) {       // order-preserving u32
    unsigned u = __float_as_uint(f);
    return (u & 0x80000000u) ? ~u : (u | 0x80000000u);
}
__device__ __forceinline__ float key2f(unsigned k) {
    return __uint_as_float((k & 0x80000000u) ? (k ^ 0x80000000u) : ~k);
}
__device__ __forceinline__ unsigned umax2(unsigned a, unsigned b) { return a > b ? a : b; }

// ---------------------------------------------------------------------------
// Kernel 1: fused projections out = X @ W^T + b (row-major head-major);
// z==1 also emits khi (bf16, MFMA B-frag order) via LDS restage + coalesced
// ushort8 stores (replaces 16 scattered u16 stores per thread).
// ---------------------------------------------------------------------------
__global__ __launch_bounds__(256) void proj_kernel(
    const float* __restrict__ Xq, const float* __restrict__ Xk, const float* __restrict__ Xv,
    const float* __restrict__ Wq, const float* __restrict__ Bq,
    const float* __restrict__ Wk, const float* __restrict__ Bk,
    const float* __restrict__ Wv, const float* __restrict__ Bv,
    float* __restrict__ ws)
{
    const int z = blockIdx.z;
    const float* X = (z == 0) ? Xq : (z == 1) ? Xk : Xv;
    const float* W = (z == 0) ? Wq : (z == 1) ? Wk : Wv;
    const float* B = (z == 0) ? Bq : (z == 1) ? Bk : Bv;
    float* out = ws + (size_t)z * 2097152;
    unsigned short* khi = (unsigned short*)(ws + 6291456);

    __shared__ float4 Xs[64 * 8];
    __shared__ float4 Ws[64 * 8];
    __shared__ unsigned short kst[64 * 72];   // bf16 tile stage (stride 72 -> 16B align)

    const int tid = threadIdx.x;
    const int tx = tid & 15, ty = tid >> 4;
    const int m0 = blockIdx.x * 64, n0 = blockIdx.y * 64;

    float acc[4][4];
    #pragma unroll
    for (int i = 0; i < 4; ++i)
        #pragma unroll
        for (int j = 0; j < 4; ++j) acc[i][j] = 0.f;

    for (int k0 = 0; k0 < HD; k0 += 32) {
        #pragma unroll
        for (int it = 0; it < 2; ++it) {
            int f = tid + it * 256;
            int row = f >> 3, c = f & 7;
            int cs = c ^ ((row >> 2) & 7);
            Xs[row * 8 + cs] = *(const float4*)&X[(size_t)(m0 + row) * HD + k0 + c * 4];
            Ws[row * 8 + cs] = *(const float4*)&W[(size_t)(n0 + row) * HD + k0 + c * 4];
        }
        __syncthreads();
        #pragma unroll
        for (int c = 0; c < 8; ++c) {
            float4 av[4], bv4[4];
            #pragma unroll
            for (int i = 0; i < 4; ++i) { int r = ty * 4 + i; av[i]  = Xs[r * 8 + (c ^ ((r >> 2) & 7))]; }
            #pragma unroll
            for (int j = 0; j < 4; ++j) { int r = tx * 4 + j; bv4[j] = Ws[r * 8 + (c ^ ((r >> 2) & 7))]; }
            #pragma unroll
            for (int i = 0; i < 4; ++i)
                #pragma unroll
                for (int j = 0; j < 4; ++j) {
                    acc[i][j] = fmaf(av[i].x, bv4[j].x, acc[i][j]);
                    acc[i][j] = fmaf(av[i].y, bv4[j].y, acc[i][j]);
                    acc[i][j] = fmaf(av[i].z, bv4[j].z, acc[i][j]);
                    acc[i][j] = fmaf(av[i].w, bv4[j].w, acc[i][j]);
                }
        }
        __syncthreads();
    }

    #pragma unroll
    for (int j = 0; j < 4; ++j) {
        int o = n0 + tx * 4 + j;
        float bb = B[o];
        int h = o >> 6, e = o & 63;
        #pragma unroll
        for (int i = 0; i < 4; ++i) {
            int m = m0 + ty * 4 + i;
            int n = m >> 11, s = m & 2047;
            float val = acc[i][j] + bb;
            int head = n * NH + h;
            out[(size_t)head * 131072 + (size_t)s * EH + e] = val;
            if (z == 1) kst[(ty * 4 + i) * 72 + e] = f2b(val);
        }
    }

    if (z == 1) {
        __syncthreads();
        const int head = (m0 >> 11) * NH + (n0 >> 6);
        const int kt0  = (m0 & 2047) >> 4;
        #pragma unroll
        for (int it = 0; it < 2; ++it) {
            int g = tid + it * 256;                 // 512 frags: 4 kt x 2 ks x 64 lanes
            int lane_g = g & 63;
            int rest = g >> 6;
            int kt = rest >> 1, ksb = rest & 1;
            int s_loc = kt * 16 + (lane_g & 15);
            int e0 = ksb * 32 + ((lane_g >> 4) << 3);
            u16x8 vv = *(const u16x8*)&kst[s_loc * 72 + e0];
            size_t idx = ((((size_t)head * 128 + (kt0 + kt)) * 2 + ksb) * 64 + lane_g) * 8;
            *(u16x8*)&khi[idx] = vv;
        }
    }
}

// ---------------------------------------------------------------------------
// Kernel 2: MFMA bf16 approx QK^T -> tau-margin candidates -> exact f32
// rescore -> exact top-32 (u64 bitonic, tie=lowest idx) -> softmax -> A, V.
// Block = 512 thr (8 waves), 16 q-rows, 2048 blocks. LDS 72KB -> 2 blocks/CU.
// Round-6: DS-pipe diet (readlane V-gather, ballot compaction, VMEM q-bcast).
// ---------------------------------------------------------------------------
__device__ __forceinline__ unsigned long long sort64_desc(unsigned long long v, int lane) {
    #pragma unroll
    for (int k = 2; k <= 64; k <<= 1)
        #pragma unroll
        for (int j = k >> 1; j >= 1; j >>= 1) {
            unsigned long long o = __shfl_xor(v, j, 64);
            bool up = ((lane & k) != 0);                 // flipped -> descending
            bool keepmin = (((lane & j) == 0) == up);
            unsigned long long lo = v < o ? v : o;
            unsigned long long hi = v > o ? v : o;
            v = keepmin ? lo : hi;
        }
    return v;
}
__device__ __forceinline__ unsigned long long merge_top64(unsigned long long a, unsigned long long b, int lane) {
    unsigned long long br = __shfl(b, 63 - lane, 64);
    unsigned long long m = a > br ? a : br;
    #pragma unroll
    for (int j = 32; j >= 1; j >>= 1) {
        unsigned long long o = __shfl_xor(m, j, 64);
        bool keepmax = ((lane & j) == 0);
        unsigned long long mx = m > o ? m : o;
        unsigned long long mn = m < o ? m : o;
        m = keepmax ? mx : mn;
    }
    return m;
}

__global__ __launch_bounds__(512, 4) void attn_kernel(
    const float* __restrict__ ws, float* __restrict__ outV, float* __restrict__ outA)
{
    const float* qw = ws;
    const float* kw = ws + 2097152;
    const float* vw = ws + 4194304;
    const unsigned short* khi = (const unsigned short*)(ws + 6291456);

    __shared__ unsigned short scores16[16 * 2048];   // 65536 B (u16 sortable keys)
    __shared__ float qs[EH * 16];                    // 4096 B, [e][row]
    __shared__ unsigned short candArr[8 * 256];      // 4096 B

    const int tid  = threadIdx.x;
    const int lane = tid & 63;
    const int uwv  = __builtin_amdgcn_readfirstlane(tid) >> 6;  // wave id (SGPR)

    // XCD swizzle: 2048 blocks, 256/XCD = 2 heads per XCD (working set ~3.5MB in L2)
    unsigned bid = blockIdx.x;
    unsigned id  = (bid & 7u) * 256u + (bid >> 3);
    const int head = (int)(id >> 7);           // n*8+h
    const int l0   = (int)(id & 127u) * 16;
    const size_t headoff = (size_t)head * 131072;

    // stage q: qs[e][row], rows l0..l0+15
    #pragma unroll
    for (int it = 0; it < 2; ++it) {
        int i = tid + it * 512;
        int row = i & 15, e = i >> 4;
        qs[i] = qw[headoff + (size_t)(l0 + row) * EH + e];
    }
    __syncthreads();

    // ---- Phase A: MFMA approx scores -> u16 keys in LDS (fused per-kt) ----
    {
        bf16x8 afrag[2];
        #pragma unroll
        for (int ks = 0; ks < 2; ++ks)
            #pragma unroll
            for (int j = 0; j < 8; ++j) {
                int e = ks * 32 + ((lane >> 4) << 3) + j;
                afrag[ks][j] = (short)f2b(qs[e * 16 + (lane & 15)]);
            }

        #pragma unroll
        for (int kt = 0; kt < 16; ++kt) {
            f32x4 acc = (f32x4)(0.f);
            int ktg = uwv * 16 + kt;
            #pragma unroll
            for (int ks = 0; ks < 2; ++ks) {
                bf16x8 b = *(const bf16x8*)(khi + (size_t)head * 131072 +
                              ((((size_t)ktg * 2 + ks) * 64 + lane) << 3));
                acc = __builtin_amdgcn_mfma_f32_16x16x32_bf16(afrag[ks], b, acc, 0, 0, 0);
            }
            int key = uwv * 256 + kt * 16 + (lane & 15);
            int rbase = (lane >> 4) << 2;          // C: col=lane&15, row=(lane>>4)*4+reg
            #pragma unroll
            for (int reg = 0; reg < 4; ++reg)
                scores16[(rbase + reg) * 2048 + key] = (unsigned short)(f2key(acc[reg]) >> 16);
        }
    }
    __syncthreads();

    // ---- Select: wave uwv owns rows 2uwv, 2uwv+1; fully wave-local ----
    unsigned short* cand = candArr + uwv * 256;
    const unsigned long long lmlt = (1ull << lane) - 1ull;
    int selS[2]; float selW[2];

    #pragma unroll
    for (int rr2 = 0; rr2 < 2; ++rr2) {
        const int r = 2 * uwv + rr2;
        const int lrow = l0 + r;
        const unsigned* srow32 = (const unsigned*)(scores16 + r * 2048);

        // keys into registers (reused for max + compaction)
        unsigned pk[16];
        #pragma unroll
        for (int t = 0; t < 16; ++t) pk[t] = srow32[t * 64 + lane];

        // 1. per-lane max over packed u16 pairs
        unsigned mx = 0;
        #pragma unroll
        for (int t = 0; t < 16; ++t) {
            unsigned a = pk[t] & 0xFFFFu, b = pk[t] >> 16;
            mx = umax2(mx, umax2(a, b));
        }
        // 2. bitonic ascending sort of lane maxima; tau16 = rank-32 (lane 32)
        {
            unsigned v = mx;
            #pragma unroll
            for (int k = 2; k <= 64; k <<= 1)
                #pragma unroll
                for (int j = k >> 1; j >= 1; j >>= 1) {
                    unsigned o = __shfl_xor(v, j);
                    bool up = ((lane & k) == 0);
                    bool keepmin = (((lane & j) == 0) == up);
                    unsigned lo = v < o ? v : o, hi = v > o ? v : o;
                    v = keepmin ? lo : hi;
                }
            mx = __shfl(v, 32);
        }
        const unsigned tau16 = mx;
        const float tauf = key2f(tau16 << 16);
        const unsigned thr16 = f2key(tauf - 0.35f) >> 16;   // margin: bf16+trunc error

        // 3. ballot-prefix compaction (unordered ok; sort settles ties by index)
        int Nc = 0;
        #pragma unroll
        for (int t = 0; t < 16; ++t) {
            unsigned vv = pk[t];
            unsigned i0 = (unsigned)((t * 64 + lane) * 2);
            bool c0 = (vv & 0xFFFFu) >= thr16;
            bool c1 = (vv >> 16) >= thr16;
            unsigned long long b0 = __ballot(c0);
            if (c0) {
                int p = Nc + __popcll(b0 & lmlt);
                if (p < 256) cand[p] = (unsigned short)i0;
            }
            Nc += __popcll(b0);
            unsigned long long b1 = __ballot(c1);
            if (c1) {
                int p = Nc + __popcll(b1 & lmlt);
                if (p < 256) cand[p] = (unsigned short)(i0 + 1);
            }
            Nc += __popcll(b1);
        }
        if (Nc > 256) Nc = 256;
        const int nch = (Nc + 63) >> 6;

        // 4. q row via wave-uniform global loads (VMEM broadcast, off DS pipe)
        const float* qrow = qw + headoff + (size_t)lrow * EH;
        float4 qv[16];
        #pragma unroll
        for (int c4 = 0; c4 < 16; ++c4) qv[c4] = *(const float4*)&qrow[c4 * 4];

        // 5. exact rescore + exact top-32 via u64 bitonic (desc), chunk-merged
        unsigned long long best = 0ull;
        for (int c = 0; c < nch; ++c) {
            int p = c * 64 + lane;
            bool valid = p < Nc;
            int si = valid ? (int)cand[p] : 0;
            const float* krow = kw + headoff + (size_t)si * EH;
            float sc = 0.f;
            #pragma unroll
            for (int c4 = 0; c4 < 16; ++c4) {      // ascending e: matches round-5
                float4 kv = *(const float4*)&krow[c4 * 4];
                sc = fmaf(qv[c4].x, kv.x, sc);
                sc = fmaf(qv[c4].y, kv.y, sc);
                sc = fmaf(qv[c4].z, kv.z, sc);
                sc = fmaf(qv[c4].w, kv.w, sc);
            }
            unsigned long long comp = valid
                ? ((((unsigned long long)f2key(sc)) << 32) | (unsigned)(~si))
                : 0ull;
            comp = sort64_desc(comp, lane);
            best = (c == 0) ? comp : merge_top64(best, comp, lane);
        }

        // 6. softmax over lanes 0..31 (desc order; lane0 = max)
        unsigned key32 = (unsigned)(best >> 32);
        int si = (int)(~((unsigned)best)) & 2047;
        float sc = key2f(key32);
        float M = __shfl(sc, 0);
        float ee = (lane < TK) ? __expf(0.125f * (sc - M)) : 0.f;
        float Z = ee;
        #pragma unroll
        for (int d = 1; d < 64; d <<= 1) Z += __shfl_xor(Z, d);
        selS[rr2] = si;
        selW[rr2] = ee / Z;
    }

    // ---- Epilogue (keys dead): A rows staged in wave-private 8KB + V rows ----
    float* abuf = (float*)((char*)scores16 + uwv * 8192);   // rows 2uwv..2uwv+1 area
    #pragma unroll
    for (int rr2 = 0; rr2 < 2; ++rr2) {
        const int lrow = l0 + 2 * uwv + rr2;
        float4* ab4 = (float4*)abuf;
        const float4 z4 = make_float4(0.f, 0.f, 0.f, 0.f);
        #pragma unroll
        for (int u = 0; u < 8; ++u) ab4[u * 64 + lane] = z4;
        if (lane < TK) abuf[selS[rr2]] = selW[rr2];          // wave-local scatter
        float* Arow = outA + ((size_t)head * 2048 + lrow) * 2048;
        #pragma unroll
        for (int u = 0; u < 8; ++u)
            *(float4*)&Arow[(u * 64 + lane) * 4] = ab4[u * 64 + lane];

        // V: broadcast slots via readlane (VALU) -> saddr-form coalesced loads
        float acc = 0.f;
        int   siv = selS[rr2];
        unsigned wbits = __float_as_uint(selW[rr2]);
        #pragma unroll
        for (int i = 0; i < TK; ++i) {
            int s_i   = __builtin_amdgcn_readlane(siv, i);
            float w_i = __uint_as_float((unsigned)__builtin_amdgcn_readlane((int)wbits, i));
            acc = fmaf(w_i, vw[headoff + (size_t)s_i * EH + lane], acc);
        }
        const int n = head >> 3, h = head & 7;
        outV[((size_t)(n * 2048 + lrow)) * 512 + h * 64 + lane] = acc;
    }
}

// ---------------------------------------------------------------------------
extern "C" void kernel_launch(void* const* d_in, const int* in_sizes, int n_in,
                              void* d_out, int out_size, void* d_ws, size_t ws_size,
                              hipStream_t stream)
{
    (void)in_sizes; (void)n_in; (void)out_size; (void)ws_size;
    const float* q  = (const float*)d_in[0];
    const float* k  = (const float*)d_in[1];
    const float* v  = (const float*)d_in[2];
    const float* Wq = (const float*)d_in[3];
    const float* bq = (const float*)d_in[4];
    const float* Wk = (const float*)d_in[5];
    const float* bk = (const float*)d_in[6];
    const float* Wv = (const float*)d_in[7];
    const float* bv = (const float*)d_in[8];
    float* ws   = (float*)d_ws;  // 28 MiB
    float* outV = (float*)d_out;
    float* outA = outV + (size_t)NBATCH * LSEQ * HD;

    proj_kernel<<<dim3(64, 8, 3), 256, 0, stream>>>(q, k, v, Wq, bq, Wk, bk, Wv, bv, ws);
    attn_kernel<<<dim3(2048, 1, 1), 512, 0, stream>>>(ws, outV, outA);
}